// Round 1
// baseline (5118.895 us; speedup 1.0000x reference)
//
#include <hip/hip_runtime.h>
#include <math.h>

constexpr int NPTS = 8192;
constexpr int INC  = 3;
constexpr int HIDC = 128;
constexpr int OUTC2 = 256;
constexpr int KK1  = 16;
constexpr int KK2  = 8;

// ---------------------------------------------------------------- sq norms
__global__ void sqnorm3_kernel(const float* __restrict__ x, float* __restrict__ sq) {
    int i = blockIdx.x * blockDim.x + threadIdx.x;
    if (i < NPTS) {
        float a = x[i * 3 + 0], b = x[i * 3 + 1], c = x[i * 3 + 2];
        sq[i] = a * a + b * b + c * c;
    }
}

__global__ void sqnorm128_kernel(const float* __restrict__ h, float* __restrict__ sq) {
    int i = blockIdx.x;   // row
    int t = threadIdx.x;  // 128
    __shared__ float s[128];
    float v = h[(size_t)i * HIDC + t];
    s[t] = v * v;
    __syncthreads();
    for (int off = 64; off > 0; off >>= 1) {
        if (t < off) s[t] += s[t + off];
        __syncthreads();
    }
    if (t == 0) sq[i] = s[0];
}

// ---------------------------------------------------------------- brute KNN
// One block per query row i. Distances for all j staged in LDS, then K
// iterative argmin passes with lexicographic (dist, idx) tie-break — matches
// jax.lax.top_k(-d, k)'s stable smallest-index-on-tie behavior.
template <int C, int K>
__global__ __launch_bounds__(256) void knn_kernel(const float* __restrict__ X,
                                                  const float* __restrict__ sq,
                                                  int* __restrict__ idx_out) {
    const int i = blockIdx.x;
    const int t = threadIdx.x;
    __shared__ float dist[NPTS];   // 32 KB
    __shared__ float xi[C];
    __shared__ float sval[256];
    __shared__ int   sidx[256];

    for (int c = t; c < C; c += 256) xi[c] = X[(size_t)i * C + c];
    __syncthreads();

    const float sqi = sq[i];
    for (int j = t; j < NPTS; j += 256) {
        float dot = 0.f;
        if constexpr (C % 4 == 0) {
            const float4* xr = reinterpret_cast<const float4*>(X + (size_t)j * C);
            #pragma unroll
            for (int c4 = 0; c4 < C / 4; ++c4) {
                float4 a = *reinterpret_cast<const float4*>(&xi[c4 * 4]);
                float4 b = xr[c4];
                dot += a.x * b.x + a.y * b.y + a.z * b.z + a.w * b.w;
            }
        } else {
            #pragma unroll
            for (int c = 0; c < C; ++c) dot += xi[c] * X[(size_t)j * C + c];
        }
        float d = sqi + sq[j] - 2.f * dot;
        dist[j] = (j == i) ? INFINITY : d;
    }
    __syncthreads();

    for (int kk = 0; kk < K; ++kk) {
        float bv = INFINITY;
        int   bi = NPTS;
        for (int j = t; j < NPTS; j += 256) {
            float v = dist[j];
            if (v < bv) { bv = v; bi = j; }   // j ascending: keeps smallest idx on tie
        }
        sval[t] = bv; sidx[t] = bi;
        __syncthreads();
        for (int off = 128; off > 0; off >>= 1) {
            if (t < off) {
                float ov = sval[t + off]; int oi = sidx[t + off];
                float cv = sval[t];       int ci = sidx[t];
                if (ov < cv || (ov == cv && oi < ci)) { sval[t] = ov; sidx[t] = oi; }
            }
            __syncthreads();
        }
        if (t == 0) {
            int b = sidx[0];
            idx_out[(size_t)i * K + kk] = b;
            dist[b] = INFINITY;
        }
        __syncthreads();
    }
}

// ---------------------------------------------------------------- EdgeConv 1
// Block per point, 128 threads (one per HID channel).
__global__ __launch_bounds__(128) void edgeconv1_kernel(
        const float* __restrict__ X, const int* __restrict__ knn,
        const float* __restrict__ W1, const float* __restrict__ b1,
        const float* __restrict__ W2, const float* __restrict__ b2,
        float* __restrict__ H) {
    const int i = blockIdx.x;
    const int t = threadIdx.x;  // 128
    __shared__ float h1[KK1][HIDC];   // 8 KB
    __shared__ float xj[KK1][4];
    __shared__ float xi[4];

    if (t < 3) xi[t] = X[i * 3 + t];
    if (t < KK1) {
        int j = knn[i * KK1 + t];
        xj[t][0] = X[j * 3 + 0];
        xj[t][1] = X[j * 3 + 1];
        xj[t][2] = X[j * 3 + 2];
    }
    __syncthreads();

    float w[6];
    #pragma unroll
    for (int c = 0; c < 6; ++c) w[c] = W1[c * HIDC + t];
    const float bb  = b1[t];
    const float xi0 = xi[0], xi1 = xi[1], xi2 = xi[2];
    const float base = bb + xi0 * w[0] + xi1 * w[1] + xi2 * w[2];
    #pragma unroll
    for (int e = 0; e < KK1; ++e) {
        float v = base + (xj[e][0] - xi0) * w[3] + (xj[e][1] - xi1) * w[4] + (xj[e][2] - xi2) * w[5];
        h1[e][t] = fmaxf(v, 0.f);
    }
    __syncthreads();

    float acc[KK1];
    const float b2t = b2[t];
    #pragma unroll
    for (int e = 0; e < KK1; ++e) acc[e] = b2t;
    for (int c4 = 0; c4 < HIDC / 4; ++c4) {
        float w0 = W2[(c4 * 4 + 0) * HIDC + t];
        float w1 = W2[(c4 * 4 + 1) * HIDC + t];
        float w2 = W2[(c4 * 4 + 2) * HIDC + t];
        float w3 = W2[(c4 * 4 + 3) * HIDC + t];
        #pragma unroll
        for (int e = 0; e < KK1; ++e) {
            float4 hv = *reinterpret_cast<const float4*>(&h1[e][c4 * 4]);
            acc[e] += hv.x * w0 + hv.y * w1 + hv.z * w2 + hv.w * w3;
        }
    }
    float m = -INFINITY;
    #pragma unroll
    for (int e = 0; e < KK1; ++e) m = fmaxf(m, acc[e]);
    H[(size_t)i * HIDC + t] = m;
}

// ---------------------------------------------------------------- EdgeConv 2
// Block per point, 256 threads (one per OUT channel).
__global__ __launch_bounds__(256) void edgeconv2_kernel(
        const float* __restrict__ H, const int* __restrict__ knn,
        const float* __restrict__ W1, const float* __restrict__ b1,
        const float* __restrict__ W2, const float* __restrict__ b2,
        float* __restrict__ Out) {
    const int i = blockIdx.x;
    const int t = threadIdx.x;  // 256
    __shared__ float hi[HIDC];          // 0.5 KB
    __shared__ float hj[KK2][HIDC];     // 4 KB
    __shared__ float g1[KK2][OUTC2];    // 8 KB

    if (t < HIDC) hi[t] = H[(size_t)i * HIDC + t];
    for (int u = t; u < KK2 * HIDC; u += 256) {
        int e = u >> 7, c = u & 127;
        hj[e][c] = H[(size_t)knn[i * KK2 + e] * HIDC + c];
    }
    __syncthreads();

    // stage 1: g1[e][t] = relu([hi, hj-hi] @ W1 + b1)
    float acc[KK2];
    const float b1t = b1[t];
    #pragma unroll
    for (int e = 0; e < KK2; ++e) acc[e] = b1t;
    for (int c4 = 0; c4 < HIDC / 4; ++c4) {
        float wl[4], wh[4];
        #pragma unroll
        for (int q = 0; q < 4; ++q) {
            wl[q] = W1[(c4 * 4 + q) * OUTC2 + t];
            wh[q] = W1[(HIDC + c4 * 4 + q) * OUTC2 + t];
        }
        float4 hv = *reinterpret_cast<const float4*>(&hi[c4 * 4]);
        #pragma unroll
        for (int e = 0; e < KK2; ++e) {
            float4 jv = *reinterpret_cast<const float4*>(&hj[e][c4 * 4]);
            acc[e] += (hv.x * wl[0] + (jv.x - hv.x) * wh[0])
                    + (hv.y * wl[1] + (jv.y - hv.y) * wh[1])
                    + (hv.z * wl[2] + (jv.z - hv.z) * wh[2])
                    + (hv.w * wl[3] + (jv.w - hv.w) * wh[3]);
        }
    }
    #pragma unroll
    for (int e = 0; e < KK2; ++e) g1[e][t] = fmaxf(acc[e], 0.f);
    __syncthreads();

    // stage 2: out[t] = max_e (g1[e] @ W2 + b2)
    float acc2[KK2];
    const float b2t = b2[t];
    #pragma unroll
    for (int e = 0; e < KK2; ++e) acc2[e] = b2t;
    for (int c4 = 0; c4 < OUTC2 / 4; ++c4) {
        float w0 = W2[(c4 * 4 + 0) * OUTC2 + t];
        float w1 = W2[(c4 * 4 + 1) * OUTC2 + t];
        float w2 = W2[(c4 * 4 + 2) * OUTC2 + t];
        float w3 = W2[(c4 * 4 + 3) * OUTC2 + t];
        #pragma unroll
        for (int e = 0; e < KK2; ++e) {
            float4 gv = *reinterpret_cast<const float4*>(&g1[e][c4 * 4]);
            acc2[e] += gv.x * w0 + gv.y * w1 + gv.z * w2 + gv.w * w3;
        }
    }
    float m = -INFINITY;
    #pragma unroll
    for (int e = 0; e < KK2; ++e) m = fmaxf(m, acc2[e]);
    Out[(size_t)i * OUTC2 + t] = m;
}

// ---------------------------------------------------------------- launch
extern "C" void kernel_launch(void* const* d_in, const int* in_sizes, int n_in,
                              void* d_out, int out_size, void* d_ws, size_t ws_size,
                              hipStream_t stream) {
    const float* x   = (const float*)d_in[0];
    const float* W1a = (const float*)d_in[1];
    const float* b1a = (const float*)d_in[2];
    const float* W1b = (const float*)d_in[3];
    const float* b1b = (const float*)d_in[4];
    const float* W2a = (const float*)d_in[5];
    const float* b2a = (const float*)d_in[6];
    const float* W2b = (const float*)d_in[7];
    const float* b2b = (const float*)d_in[8];
    float* out = (float*)d_out;

    // workspace layout (all 16B-aligned)
    float* h   = (float*)d_ws;                   // N*128 floats = 4 MB
    float* sq1 = h + (size_t)NPTS * HIDC;        // N floats
    float* sq2 = sq1 + NPTS;                     // N floats
    int*   idx1 = (int*)(sq2 + NPTS);            // N*16 ints
    int*   idx2 = idx1 + (size_t)NPTS * KK1;     // N*8 ints

    sqnorm3_kernel<<<(NPTS + 255) / 256, 256, 0, stream>>>(x, sq1);
    knn_kernel<INC, KK1><<<NPTS, 256, 0, stream>>>(x, sq1, idx1);
    edgeconv1_kernel<<<NPTS, 128, 0, stream>>>(x, idx1, W1a, b1a, W1b, b1b, h);
    sqnorm128_kernel<<<NPTS, 128, 0, stream>>>(h, sq2);
    knn_kernel<HIDC, KK2><<<NPTS, 256, 0, stream>>>(h, sq2, idx2);
    edgeconv2_kernel<<<NPTS, 256, 0, stream>>>(h, idx2, W2a, b2a, W2b, b2b, out);
}

// Round 2
// 1623.006 us; speedup vs baseline: 3.1540x; 3.1540x over previous
//
#include <hip/hip_runtime.h>
#include <math.h>

constexpr int NPTS  = 8192;
constexpr int HIDC  = 128;
constexpr int OUTC2 = 256;
constexpr int KK1   = 16;
constexpr int KK2   = 8;

__device__ __forceinline__ void async_ld16(void* lds, const void* g) {
  __builtin_amdgcn_global_load_lds(
      (const __attribute__((address_space(1))) unsigned int*)g,
      (__attribute__((address_space(3))) unsigned int*)lds, 16, 0, 0);
}

__device__ __forceinline__ float dot4f(float4 a, float4 b) {
  return a.x * b.x + a.y * b.y + a.z * b.z + a.w * b.w;
}

// sorted ascending by (f, idx); insert keeps exact lexicographic top-K.
template <int K>
__device__ __forceinline__ void topk_insert(float (&kf)[K], int (&ki)[K], float v, int j) {
  bool ins = (v < kf[K - 1]) || (v == kf[K - 1] && j < ki[K - 1]);
  if (ins) {
    kf[K - 1] = v; ki[K - 1] = j;
    #pragma unroll
    for (int p = K - 1; p > 0; --p) {
      float fa = kf[p - 1], fb = kf[p];
      int   ia = ki[p - 1], ib = ki[p];
      bool sw = (fb < fa) || (fb == fa && ib < ia);
      kf[p - 1] = sw ? fb : fa; ki[p - 1] = sw ? ib : ia;
      kf[p]     = sw ? fa : fb; ki[p]     = sw ? ia : ib;
    }
  }
}

// ---------------------------------------------------------------- pack x
__global__ void pack_x_kernel(const float* __restrict__ x, float4* __restrict__ x4) {
  int i = blockIdx.x * blockDim.x + threadIdx.x;
  if (i < NPTS) {
    float a = x[3 * i], b = x[3 * i + 1], c = x[3 * i + 2];
    x4[i] = make_float4(a, b, c, a * a + b * b + c * c);
  }
}

__global__ void sqnorm128_kernel(const float* __restrict__ h, float* __restrict__ sq) {
  int i = blockIdx.x;
  int t = threadIdx.x;
  __shared__ float s[128];
  float v = h[(size_t)i * HIDC + t];
  s[t] = v * v;
  __syncthreads();
  for (int off = 64; off > 0; off >>= 1) {
    if (t < off) s[t] += s[t + off];
    __syncthreads();
  }
  if (t == 0) sq[i] = s[0];
}

// ---------------------------------------------------------------- KNN1 (C=3, K=16)
// 512 thr, 32 queries/block (wave -> 4 queries), JT=256 j per chunk read
// straight from global (tiny data, L2-resident). D-tile -> streaming topk.
constexpr int Q1 = 32, JT1 = 256, NC1 = NPTS / JT1, PARTS1 = 16, JPP1 = JT1 / PARTS1;
constexpr int MS1 = PARTS1 * KK1 + 4;  // merge row stride (pad)

__global__ __launch_bounds__(512) void knn3_kernel(const float4* __restrict__ X4,
                                                   int* __restrict__ out) {
  __shared__ float Dt[Q1][JT1 + 4];
  __shared__ float mf[Q1 * MS1];
  __shared__ int   mi[Q1 * MS1];
  const int tid  = threadIdx.x;
  const int lane = tid & 63;
  const int wv   = __builtin_amdgcn_readfirstlane(tid >> 6);
  const int qg0  = blockIdx.x * Q1 + 4 * wv;

  const float4 qv0 = X4[qg0], qv1 = X4[qg0 + 1], qv2 = X4[qg0 + 2], qv3 = X4[qg0 + 3];
  float qx[4] = {qv0.x, qv1.x, qv2.x, qv3.x};
  float qy[4] = {qv0.y, qv1.y, qv2.y, qv3.y};
  float qz[4] = {qv0.z, qv1.z, qv2.z, qv3.z};
  float qw[4] = {qv0.w, qv1.w, qv2.w, qv3.w};

  float kf[KK1]; int ki[KK1];
  #pragma unroll
  for (int k = 0; k < KK1; ++k) { kf[k] = INFINITY; ki[k] = 0x7fffffff; }
  const int sq_q = tid >> 4;   // 0..31
  const int sq_p = tid & 15;   // 0..15

  for (int ch = 0; ch < NC1; ++ch) {
    const int j0 = ch * JT1;
    float4 jv[4];
    #pragma unroll
    for (int ji = 0; ji < 4; ++ji) jv[ji] = X4[j0 + 4 * lane + ji];
    #pragma unroll
    for (int qi = 0; qi < 4; ++qi) {
      float d[4];
      #pragma unroll
      for (int ji = 0; ji < 4; ++ji) {
        float dot = qx[qi] * jv[ji].x + qy[qi] * jv[ji].y + qz[qi] * jv[ji].z;
        d[ji] = qw[qi] + jv[ji].w - 2.f * dot;
        if (j0 + 4 * lane + ji == qg0 + qi) d[ji] = INFINITY;
      }
      *(float4*)&Dt[4 * wv + qi][4 * lane] = make_float4(d[0], d[1], d[2], d[3]);
    }
    __syncthreads();
    #pragma unroll
    for (int s = 0; s < JPP1; ++s) {
      int jl = sq_p * JPP1 + s;
      topk_insert<KK1>(kf, ki, Dt[sq_q][jl], j0 + jl);
    }
    __syncthreads();
  }
  #pragma unroll
  for (int k = 0; k < KK1; ++k) {
    mf[sq_q * MS1 + sq_p * KK1 + k] = kf[k];
    mi[sq_q * MS1 + sq_p * KK1 + k] = ki[k];
  }
  __syncthreads();
  if (tid < Q1) {
    float bf[KK1]; int bi[KK1];
    #pragma unroll
    for (int k = 0; k < KK1; ++k) { bf[k] = INFINITY; bi[k] = 0x7fffffff; }
    for (int t = 0; t < PARTS1 * KK1; ++t)
      topk_insert<KK1>(bf, bi, mf[tid * MS1 + t], mi[tid * MS1 + t]);
    int qg = blockIdx.x * Q1 + tid;
    #pragma unroll
    for (int k = 0; k < KK1; ++k) out[qg * KK1 + k] = bi[k];
  }
}

// ---------------------------------------------------------------- KNN2 (C=128, K=8)
// 512 thr, 32 queries/block. q via uniform scalar loads; j-panel double-
// buffered in LDS via global_load_lds with pre-swizzled source (slot ^ (row>>2)&7)
// so hot-loop ds_read_b128 spreads over 8 bank groups. Counted vmcnt waits.
constexpr int Q2 = 32, JT2 = 128, NC2 = NPTS / JT2, PARTS2 = 16, JPP2 = JT2 / PARTS2;
constexpr int MS2 = PARTS2 * KK2 + 4;

__global__ __launch_bounds__(512) void knn128_kernel(const float* __restrict__ H,
                                                     const float* __restrict__ SQ,
                                                     int* __restrict__ out) {
  __shared__ float js[2][JT2 * HIDC];   // 2 x 64 KB
  __shared__ float Dt[Q2][JT2 + 4];     // 16.9 KB
  const int tid  = threadIdx.x;
  const int lane = tid & 63;
  const int wv   = __builtin_amdgcn_readfirstlane(tid >> 6);
  const int qg0  = blockIdx.x * Q2 + 4 * wv;

  const float* qp[4];
  #pragma unroll
  for (int qi = 0; qi < 4; ++qi) qp[qi] = H + (size_t)(qg0 + qi) * HIDC;
  float sqq[4];
  #pragma unroll
  for (int qi = 0; qi < 4; ++qi) sqq[qi] = SQ[qg0 + qi];

  float kf[KK2]; int ki[KK2];
  #pragma unroll
  for (int k = 0; k < KK2; ++k) { kf[k] = INFINITY; ki[k] = 0x7fffffff; }
  const int sq_q = tid >> 4;
  const int sq_p = tid & 15;

  auto stage = [&](int buf, int ch) {
    const int j0 = ch * JT2;
    #pragma unroll
    for (int it = 0; it < 8; ++it) {
      int r = it * 16 + (tid >> 5);          // 0..127 local row
      int s = tid & 31;                      // float4 slot
      int ssw = s ^ ((r >> 2) & 7);          // pre-swizzled source slot
      const float* src = H + (size_t)(j0 + r) * HIDC + 4 * ssw;
      float* dst = &js[buf][(it * 16 + 2 * wv) * HIDC];  // wave-uniform base
      async_ld16(dst, src);
    }
  };

  stage(0, 0);
  stage(1, 1);

  for (int ch = 0; ch < NC2; ++ch) {
    const int cur = ch & 1;
    const int j0  = ch * JT2;
    if (ch == NC2 - 1) asm volatile("s_waitcnt vmcnt(0)" ::: "memory");
    else               asm volatile("s_waitcnt vmcnt(8)" ::: "memory");
    __syncthreads();

    // ---- compute 4q x 2j dot products
    const float* jb0 = &js[cur][(2 * lane) * HIDC];
    const float* jb1 = jb0 + HIDC;
    const int fsw = (lane >> 1) & 7;
    float acc[4][2] = {};
    #pragma unroll 4
    for (int c4 = 0; c4 < 32; ++c4) {
      const int off = 4 * (c4 ^ fsw);
      float4 j0v = *(const float4*)(jb0 + off);
      float4 j1v = *(const float4*)(jb1 + off);
      float4 qv[4];
      #pragma unroll
      for (int qi = 0; qi < 4; ++qi) qv[qi] = *(const float4*)(qp[qi] + 4 * c4);
      #pragma unroll
      for (int qi = 0; qi < 4; ++qi) {
        acc[qi][0] += dot4f(qv[qi], j0v);
        acc[qi][1] += dot4f(qv[qi], j1v);
      }
    }
    const int gj0 = j0 + 2 * lane;
    float2 sqj = *(const float2*)&SQ[gj0];
    #pragma unroll
    for (int qi = 0; qi < 4; ++qi) {
      float d0 = sqq[qi] + sqj.x - 2.f * acc[qi][0];
      float d1 = sqq[qi] + sqj.y - 2.f * acc[qi][1];
      if (gj0 == qg0 + qi)     d0 = INFINITY;
      if (gj0 + 1 == qg0 + qi) d1 = INFINITY;
      *(float2*)&Dt[4 * wv + qi][2 * lane] = make_float2(d0, d1);
    }
    __syncthreads();
    if (ch + 2 < NC2) stage(cur, ch + 2);
    // ---- scan D
    #pragma unroll
    for (int s = 0; s < JPP2; ++s) {
      int jl = sq_p * JPP2 + s;
      topk_insert<KK2>(kf, ki, Dt[sq_q][jl], j0 + jl);
    }
  }
  __syncthreads();
  // merge buffers overlay js[0] (dead after last chunk)
  float* mf = &js[0][0];
  int*   mi = (int*)&js[0][Q2 * MS2];
  #pragma unroll
  for (int k = 0; k < KK2; ++k) {
    mf[sq_q * MS2 + sq_p * KK2 + k] = kf[k];
    mi[sq_q * MS2 + sq_p * KK2 + k] = ki[k];
  }
  __syncthreads();
  if (tid < Q2) {
    float bf[KK2]; int bi[KK2];
    #pragma unroll
    for (int k = 0; k < KK2; ++k) { bf[k] = INFINITY; bi[k] = 0x7fffffff; }
    for (int t = 0; t < PARTS2 * KK2; ++t)
      topk_insert<KK2>(bf, bi, mf[tid * MS2 + t], mi[tid * MS2 + t]);
    int qg = blockIdx.x * Q2 + tid;
    #pragma unroll
    for (int k = 0; k < KK2; ++k) out[qg * KK2 + k] = bi[k];
  }
}

// ---------------------------------------------------------------- EdgeConv 1
__global__ __launch_bounds__(128) void edgeconv1_kernel(
        const float* __restrict__ X, const int* __restrict__ knn,
        const float* __restrict__ W1, const float* __restrict__ b1,
        const float* __restrict__ W2, const float* __restrict__ b2,
        float* __restrict__ H) {
  const int i = blockIdx.x;
  const int t = threadIdx.x;
  __shared__ float h1[KK1][HIDC];
  __shared__ float xj[KK1][4];
  __shared__ float xi[4];

  if (t < 3) xi[t] = X[i * 3 + t];
  if (t < KK1) {
    int j = knn[i * KK1 + t];
    xj[t][0] = X[j * 3 + 0];
    xj[t][1] = X[j * 3 + 1];
    xj[t][2] = X[j * 3 + 2];
  }
  __syncthreads();

  float w[6];
  #pragma unroll
  for (int c = 0; c < 6; ++c) w[c] = W1[c * HIDC + t];
  const float bb  = b1[t];
  const float xi0 = xi[0], xi1 = xi[1], xi2 = xi[2];
  const float base = bb + xi0 * w[0] + xi1 * w[1] + xi2 * w[2];
  #pragma unroll
  for (int e = 0; e < KK1; ++e) {
    float v = base + (xj[e][0] - xi0) * w[3] + (xj[e][1] - xi1) * w[4] + (xj[e][2] - xi2) * w[5];
    h1[e][t] = fmaxf(v, 0.f);
  }
  __syncthreads();

  float acc[KK1];
  const float b2t = b2[t];
  #pragma unroll
  for (int e = 0; e < KK1; ++e) acc[e] = b2t;
  for (int c4 = 0; c4 < HIDC / 4; ++c4) {
    float w0 = W2[(c4 * 4 + 0) * HIDC + t];
    float w1 = W2[(c4 * 4 + 1) * HIDC + t];
    float w2 = W2[(c4 * 4 + 2) * HIDC + t];
    float w3 = W2[(c4 * 4 + 3) * HIDC + t];
    #pragma unroll
    for (int e = 0; e < KK1; ++e) {
      float4 hv = *reinterpret_cast<const float4*>(&h1[e][c4 * 4]);
      acc[e] += hv.x * w0 + hv.y * w1 + hv.z * w2 + hv.w * w3;
    }
  }
  float m = -INFINITY;
  #pragma unroll
  for (int e = 0; e < KK1; ++e) m = fmaxf(m, acc[e]);
  H[(size_t)i * HIDC + t] = m;
}

// ---------------------------------------------------------------- EdgeConv 2
__global__ __launch_bounds__(256) void edgeconv2_kernel(
        const float* __restrict__ H, const int* __restrict__ knn,
        const float* __restrict__ W1, const float* __restrict__ b1,
        const float* __restrict__ W2, const float* __restrict__ b2,
        float* __restrict__ Out) {
  const int i = blockIdx.x;
  const int t = threadIdx.x;
  __shared__ float hi[HIDC];
  __shared__ float hj[KK2][HIDC];
  __shared__ float g1[KK2][OUTC2];

  if (t < HIDC) hi[t] = H[(size_t)i * HIDC + t];
  for (int u = t; u < KK2 * HIDC; u += 256) {
    int e = u >> 7, c = u & 127;
    hj[e][c] = H[(size_t)knn[i * KK2 + e] * HIDC + c];
  }
  __syncthreads();

  float acc[KK2];
  const float b1t = b1[t];
  #pragma unroll
  for (int e = 0; e < KK2; ++e) acc[e] = b1t;
  for (int c4 = 0; c4 < HIDC / 4; ++c4) {
    float wl[4], wh[4];
    #pragma unroll
    for (int q = 0; q < 4; ++q) {
      wl[q] = W1[(c4 * 4 + q) * OUTC2 + t];
      wh[q] = W1[(HIDC + c4 * 4 + q) * OUTC2 + t];
    }
    float4 hv = *reinterpret_cast<const float4*>(&hi[c4 * 4]);
    #pragma unroll
    for (int e = 0; e < KK2; ++e) {
      float4 jv = *reinterpret_cast<const float4*>(&hj[e][c4 * 4]);
      acc[e] += (hv.x * wl[0] + (jv.x - hv.x) * wh[0])
              + (hv.y * wl[1] + (jv.y - hv.y) * wh[1])
              + (hv.z * wl[2] + (jv.z - hv.z) * wh[2])
              + (hv.w * wl[3] + (jv.w - hv.w) * wh[3]);
    }
  }
  #pragma unroll
  for (int e = 0; e < KK2; ++e) g1[e][t] = fmaxf(acc[e], 0.f);
  __syncthreads();

  float acc2[KK2];
  const float b2t = b2[t];
  #pragma unroll
  for (int e = 0; e < KK2; ++e) acc2[e] = b2t;
  for (int c4 = 0; c4 < OUTC2 / 4; ++c4) {
    float w0 = W2[(c4 * 4 + 0) * OUTC2 + t];
    float w1 = W2[(c4 * 4 + 1) * OUTC2 + t];
    float w2 = W2[(c4 * 4 + 2) * OUTC2 + t];
    float w3 = W2[(c4 * 4 + 3) * OUTC2 + t];
    #pragma unroll
    for (int e = 0; e < KK2; ++e) {
      float4 gv = *reinterpret_cast<const float4*>(&g1[e][c4 * 4]);
      acc2[e] += gv.x * w0 + gv.y * w1 + gv.z * w2 + gv.w * w3;
    }
  }
  float m = -INFINITY;
  #pragma unroll
  for (int e = 0; e < KK2; ++e) m = fmaxf(m, acc2[e]);
  Out[(size_t)i * OUTC2 + t] = m;
}

// ---------------------------------------------------------------- launch
extern "C" void kernel_launch(void* const* d_in, const int* in_sizes, int n_in,
                              void* d_out, int out_size, void* d_ws, size_t ws_size,
                              hipStream_t stream) {
  const float* x   = (const float*)d_in[0];
  const float* W1a = (const float*)d_in[1];
  const float* b1a = (const float*)d_in[2];
  const float* W1b = (const float*)d_in[3];
  const float* b1b = (const float*)d_in[4];
  const float* W2a = (const float*)d_in[5];
  const float* b2a = (const float*)d_in[6];
  const float* W2b = (const float*)d_in[7];
  const float* b2b = (const float*)d_in[8];
  float* out = (float*)d_out;

  float* h    = (float*)d_ws;                 // N*128 floats = 4 MB
  float* sq2  = h + (size_t)NPTS * HIDC;      // N floats
  int*   idx1 = (int*)(sq2 + NPTS);           // N*16
  int*   idx2 = idx1 + (size_t)NPTS * KK1;    // N*8
  // x4 aliases h's first 128KB: knn3 finishes before edgeconv1 writes h.
  float4* x4 = (float4*)h;

  pack_x_kernel<<<(NPTS + 255) / 256, 256, 0, stream>>>(x, x4);
  knn3_kernel<<<NPTS / Q1, 512, 0, stream>>>(x4, idx1);
  edgeconv1_kernel<<<NPTS, 128, 0, stream>>>(x, idx1, W1a, b1a, W1b, b1b, h);
  sqnorm128_kernel<<<NPTS, 128, 0, stream>>>(h, sq2);
  knn128_kernel<<<NPTS / Q2, 512, 0, stream>>>(h, sq2, idx2);
  edgeconv2_kernel<<<NPTS, 256, 0, stream>>>(h, idx2, W2a, b2a, W2b, b2b, out);
}

// Round 4
// 1617.631 us; speedup vs baseline: 3.1644x; 1.0033x over previous
//
#include <hip/hip_runtime.h>
#include <math.h>

constexpr int NPTS  = 8192;
constexpr int HIDC  = 128;
constexpr int OUTC2 = 256;
constexpr int KK1   = 16;
constexpr int KK2   = 8;

typedef __attribute__((ext_vector_type(8))) short short8;
typedef __attribute__((ext_vector_type(4))) float f32x4;

__device__ __forceinline__ f32x4 mfma16(short8 a, short8 b, f32x4 c) {
  return __builtin_amdgcn_mfma_f32_16x16x32_bf16(a, b, c, 0, 0, 0);
}

// sorted ascending by (f, idx); insert keeps exact lexicographic top-K.
template <int K>
__device__ __forceinline__ void topk_insert(float (&kf)[K], int (&ki)[K], float v, int j) {
  bool ins = (v < kf[K - 1]) || (v == kf[K - 1] && j < ki[K - 1]);
  if (ins) {
    kf[K - 1] = v; ki[K - 1] = j;
    #pragma unroll
    for (int p = K - 1; p > 0; --p) {
      float fa = kf[p - 1], fb = kf[p];
      int   ia = ki[p - 1], ib = ki[p];
      bool sw = (fb < fa) || (fb == fa && ib < ia);
      kf[p - 1] = sw ? fb : fa; ki[p - 1] = sw ? ib : ia;
      kf[p]     = sw ? fa : fb; ki[p]     = sw ? ia : ib;
    }
  }
}

__device__ __forceinline__ unsigned short bf16_rn(float x) {
  unsigned int u = __float_as_uint(x);
  unsigned int r = u + 0x7fffu + ((u >> 16) & 1u);
  return (unsigned short)(r >> 16);
}

// ---------------------------------------------------------------- pack x
__global__ void pack_x_kernel(const float* __restrict__ x, float4* __restrict__ x4) {
  int i = blockIdx.x * blockDim.x + threadIdx.x;
  if (i < NPTS) {
    float a = x[3 * i], b = x[3 * i + 1], c = x[3 * i + 2];
    x4[i] = make_float4(a, b, c, a * a + b * b + c * c);
  }
}

// ---------------------------------------------------------------- h -> bf16 hi/lo + sqnorm
__global__ __launch_bounds__(128) void h_prep_kernel(const float* __restrict__ h,
                                                     unsigned short* __restrict__ hhi,
                                                     unsigned short* __restrict__ hlo,
                                                     float* __restrict__ sq) {
  const int i = blockIdx.x;
  const int t = threadIdx.x;
  __shared__ float s[128];
  float v = h[(size_t)i * HIDC + t];
  unsigned short hb = bf16_rn(v);
  float fh = __uint_as_float(((unsigned int)hb) << 16);
  float lo = v - fh;
  unsigned short lb = bf16_rn(lo);
  hhi[(size_t)i * HIDC + t] = hb;
  hlo[(size_t)i * HIDC + t] = lb;
  s[t] = v * v;
  __syncthreads();
  for (int off = 64; off > 0; off >>= 1) {
    if (t < off) s[t] += s[t + off];
    __syncthreads();
  }
  if (t == 0) sq[i] = s[0];
}

// ---------------------------------------------------------------- KNN1 (C=3, K=16)
constexpr int Q1 = 32, JT1 = 256, NC1 = NPTS / JT1, PARTS1 = 16, JPP1 = JT1 / PARTS1;
constexpr int MS1 = PARTS1 * KK1 + 4;

__global__ __launch_bounds__(512) void knn3_kernel(const float4* __restrict__ X4,
                                                   int* __restrict__ out) {
  __shared__ float Dt[Q1][JT1 + 4];
  __shared__ float mf[Q1 * MS1];
  __shared__ int   mi[Q1 * MS1];
  const int tid  = threadIdx.x;
  const int lane = tid & 63;
  const int wv   = __builtin_amdgcn_readfirstlane(tid >> 6);
  const int qg0  = blockIdx.x * Q1 + 4 * wv;

  const float4 qv0 = X4[qg0], qv1 = X4[qg0 + 1], qv2 = X4[qg0 + 2], qv3 = X4[qg0 + 3];
  float qx[4] = {qv0.x, qv1.x, qv2.x, qv3.x};
  float qy[4] = {qv0.y, qv1.y, qv2.y, qv3.y};
  float qz[4] = {qv0.z, qv1.z, qv2.z, qv3.z};
  float qw[4] = {qv0.w, qv1.w, qv2.w, qv3.w};

  float kf[KK1]; int ki[KK1];
  #pragma unroll
  for (int k = 0; k < KK1; ++k) { kf[k] = INFINITY; ki[k] = 0x7fffffff; }
  const int sq_q = tid >> 4;
  const int sq_p = tid & 15;

  for (int ch = 0; ch < NC1; ++ch) {
    const int j0 = ch * JT1;
    float4 jv[4];
    #pragma unroll
    for (int ji = 0; ji < 4; ++ji) jv[ji] = X4[j0 + 4 * lane + ji];
    #pragma unroll
    for (int qi = 0; qi < 4; ++qi) {
      float d[4];
      #pragma unroll
      for (int ji = 0; ji < 4; ++ji) {
        float dot = qx[qi] * jv[ji].x + qy[qi] * jv[ji].y + qz[qi] * jv[ji].z;
        d[ji] = qw[qi] + jv[ji].w - 2.f * dot;
        if (j0 + 4 * lane + ji == qg0 + qi) d[ji] = INFINITY;
      }
      *(float4*)&Dt[4 * wv + qi][4 * lane] = make_float4(d[0], d[1], d[2], d[3]);
    }
    __syncthreads();
    #pragma unroll
    for (int s = 0; s < JPP1; ++s) {
      int jl = sq_p * JPP1 + s;
      topk_insert<KK1>(kf, ki, Dt[sq_q][jl], j0 + jl);
    }
    __syncthreads();
  }
  #pragma unroll
  for (int k = 0; k < KK1; ++k) {
    mf[sq_q * MS1 + sq_p * KK1 + k] = kf[k];
    mi[sq_q * MS1 + sq_p * KK1 + k] = ki[k];
  }
  __syncthreads();
  if (tid < Q1) {
    float bf[KK1]; int bi[KK1];
    #pragma unroll
    for (int k = 0; k < KK1; ++k) { bf[k] = INFINITY; bi[k] = 0x7fffffff; }
    for (int t = 0; t < PARTS1 * KK1; ++t)
      topk_insert<KK1>(bf, bi, mf[tid * MS1 + t], mi[tid * MS1 + t]);
    int qg = blockIdx.x * Q1 + tid;
    #pragma unroll
    for (int k = 0; k < KK1; ++k) out[qg * KK1 + k] = bi[k];
  }
}

// ---------------------------------------------------------------- KNN2 candidates via MFMA bf16x2
// Approximate filter: per-split top-16 candidates per query (margin >> error
// band ~5e-3), exact fp32 rescore afterwards picks the true top-8.
constexpr int JSPLIT = 4;
constexpr int M2     = 16;                   // candidates per split
constexpr int JPB2   = NPTS / JSPLIT;        // 2048 j per block
constexpr int TPW2   = JPB2 / 4 / 16;        // 32 tiles per wave

__global__ __launch_bounds__(256) void knn128_mfma_kernel(
    const unsigned short* __restrict__ Hhi, const unsigned short* __restrict__ Hlo,
    const float* __restrict__ SQ, int* __restrict__ pi) {
  __shared__ float wmf[4][32][M2];
  __shared__ int   wmi[4][32][M2];
  const int tid  = threadIdx.x;
  const int lane = tid & 63;
  const int wv   = __builtin_amdgcn_readfirstlane(tid >> 6);
  const int qb   = blockIdx.x >> 2;
  const int js   = blockIdx.x & 3;
  const int q0   = qb * 32;
  const int col  = lane & 15;
  const int kg   = lane >> 4;          // 0..3 k-group / row-group
  const int qg0  = q0 + col;           // chain-0 query
  const int qg1  = q0 + 16 + col;      // chain-1 query

  short8 qhi0[4], qlo0[4], qhi1[4], qlo1[4];
  #pragma unroll
  for (int s = 0; s < 4; ++s) {
    const size_t o0 = (size_t)qg0 * HIDC + s * 32 + kg * 8;
    const size_t o1 = (size_t)qg1 * HIDC + s * 32 + kg * 8;
    qhi0[s] = *reinterpret_cast<const short8*>(Hhi + o0);
    qlo0[s] = *reinterpret_cast<const short8*>(Hlo + o0);
    qhi1[s] = *reinterpret_cast<const short8*>(Hhi + o1);
    qlo1[s] = *reinterpret_cast<const short8*>(Hlo + o1);
  }
  const float sqq0 = SQ[qg0];
  const float sqq1 = SQ[qg1];

  float kf0[M2], kf1[M2]; int ki0[M2], ki1[M2];
  #pragma unroll
  for (int k = 0; k < M2; ++k) {
    kf0[k] = INFINITY; ki0[k] = 0x7fffffff;
    kf1[k] = INFINITY; ki1[k] = 0x7fffffff;
  }

  const int jw0 = js * JPB2 + wv * (JPB2 / 4);
  for (int it = 0; it < TPW2; ++it) {
    const int jb = jw0 + it * 16;
    const int arow = jb + col;
    short8 ahi[4], alo[4];
    #pragma unroll
    for (int s = 0; s < 4; ++s) {
      const size_t oa = (size_t)arow * HIDC + s * 32 + kg * 8;
      ahi[s] = *reinterpret_cast<const short8*>(Hhi + oa);
      alo[s] = *reinterpret_cast<const short8*>(Hlo + oa);
    }
    f32x4 sqjv = *reinterpret_cast<const f32x4*>(SQ + jb + kg * 4);

    f32x4 acc0 = {0.f, 0.f, 0.f, 0.f}, acc1 = {0.f, 0.f, 0.f, 0.f};
    #pragma unroll
    for (int s = 0; s < 4; ++s) {
      acc0 = mfma16(ahi[s], qhi0[s], acc0);
      acc0 = mfma16(ahi[s], qlo0[s], acc0);
      acc0 = mfma16(alo[s], qhi0[s], acc0);
      acc0 = mfma16(alo[s], qlo0[s], acc0);
      acc1 = mfma16(ahi[s], qhi1[s], acc1);
      acc1 = mfma16(ahi[s], qlo1[s], acc1);
      acc1 = mfma16(alo[s], qhi1[s], acc1);
      acc1 = mfma16(alo[s], qlo1[s], acc1);
    }
    // D row = (lane>>4)*4 + reg (m89/m91 verified); col = lane&15 = query
    #pragma unroll
    for (int r = 0; r < 4; ++r) {
      const int jg = jb + kg * 4 + r;
      float d0 = sqq0 + sqjv[r] - 2.f * acc0[r];
      if (jg == qg0) d0 = INFINITY;
      topk_insert<M2>(kf0, ki0, d0, jg);
      float d1 = sqq1 + sqjv[r] - 2.f * acc1[r];
      if (jg == qg1) d1 = INFINITY;
      topk_insert<M2>(kf1, ki1, d1, jg);
    }
  }

  // butterfly merge across the 4 row-groups (lanes l^16, l^32)
  #pragma unroll
  for (int dlt = 16; dlt <= 32; dlt <<= 1) {
    float of[M2]; int oi[M2];
    #pragma unroll
    for (int k = 0; k < M2; ++k) { of[k] = __shfl_xor(kf0[k], dlt, 64); oi[k] = __shfl_xor(ki0[k], dlt, 64); }
    #pragma unroll
    for (int k = 0; k < M2; ++k) topk_insert<M2>(kf0, ki0, of[k], oi[k]);
    #pragma unroll
    for (int k = 0; k < M2; ++k) { of[k] = __shfl_xor(kf1[k], dlt, 64); oi[k] = __shfl_xor(ki1[k], dlt, 64); }
    #pragma unroll
    for (int k = 0; k < M2; ++k) topk_insert<M2>(kf1, ki1, of[k], oi[k]);
  }

  if (lane < 16) {
    #pragma unroll
    for (int k = 0; k < M2; ++k) { wmf[wv][lane][k] = kf0[k]; wmi[wv][lane][k] = ki0[k]; }
  } else if (lane < 32) {
    #pragma unroll
    for (int k = 0; k < M2; ++k) { wmf[wv][lane][k] = kf1[k]; wmi[wv][lane][k] = ki1[k]; }
  }
  __syncthreads();

  if (tid < 32) {
    float bf[M2]; int bi[M2];
    #pragma unroll
    for (int k = 0; k < M2; ++k) { bf[k] = INFINITY; bi[k] = 0x7fffffff; }
    for (int w = 0; w < 4; ++w)
      #pragma unroll
      for (int k = 0; k < M2; ++k) topk_insert<M2>(bf, bi, wmf[w][tid][k], wmi[w][tid][k]);
    const int q = q0 + tid;
    #pragma unroll
    for (int k = 0; k < M2; ++k)
      pi[((size_t)q * JSPLIT + js) * M2 + k] = bi[k];
  }
}

// ---------------------------------------------------------------- exact fp32 rescore of 64 candidates
__global__ __launch_bounds__(256) void knn_rescore_kernel(
    const float* __restrict__ H, const float* __restrict__ SQ,
    const int* __restrict__ pi, int* __restrict__ idx_out) {
  const int tid  = threadIdx.x;
  const int wv   = tid >> 6;          // query sub-index (wave per query)
  const int lane = tid & 63;          // candidate index (4 splits x 16)
  const int q0   = blockIdx.x * 4;
  const int q    = q0 + wv;
  __shared__ float qrow[4][HIDC];
  for (int u = tid; u < 4 * HIDC; u += 256)
    qrow[u >> 7][u & 127] = H[(size_t)(q0 + (u >> 7)) * HIDC + (u & 127)];
  __syncthreads();

  const int ci = pi[(size_t)q * (JSPLIT * M2) + lane];
  const float* crow = H + (size_t)ci * HIDC;
  float dot = 0.f;
  #pragma unroll
  for (int c4 = 0; c4 < HIDC / 4; ++c4) {
    float4 qv = *reinterpret_cast<const float4*>(&qrow[wv][4 * c4]);
    float4 cv = *reinterpret_cast<const float4*>(crow + 4 * c4);
    dot += qv.x * cv.x + qv.y * cv.y + qv.z * cv.z + qv.w * cv.w;
  }
  float d = SQ[q] + SQ[ci] - 2.f * dot;
  if (ci == q) d = INFINITY;  // defensive; splits exclude self already

  float kf[KK2]; int ki[KK2];
  #pragma unroll
  for (int k = 0; k < KK2; ++k) { kf[k] = INFINITY; ki[k] = 0x7fffffff; }
  topk_insert<KK2>(kf, ki, d, ci);
  #pragma unroll
  for (int dlt = 1; dlt <= 32; dlt <<= 1) {
    float of[KK2]; int oi[KK2];
    #pragma unroll
    for (int k = 0; k < KK2; ++k) { of[k] = __shfl_xor(kf[k], dlt, 64); oi[k] = __shfl_xor(ki[k], dlt, 64); }
    #pragma unroll
    for (int k = 0; k < KK2; ++k) topk_insert<KK2>(kf, ki, of[k], oi[k]);
  }
  if (lane == 0) {
    #pragma unroll
    for (int k = 0; k < KK2; ++k) idx_out[(size_t)q * KK2 + k] = ki[k];
  }
}

// ---------------------------------------------------------------- EdgeConv 1
__global__ __launch_bounds__(128) void edgeconv1_kernel(
        const float* __restrict__ X, const int* __restrict__ knn,
        const float* __restrict__ W1, const float* __restrict__ b1,
        const float* __restrict__ W2, const float* __restrict__ b2,
        float* __restrict__ H) {
  const int i = blockIdx.x;
  const int t = threadIdx.x;
  __shared__ float h1[KK1][HIDC];
  __shared__ float xj[KK1][4];
  __shared__ float xi[4];

  if (t < 3) xi[t] = X[i * 3 + t];
  if (t < KK1) {
    int j = knn[i * KK1 + t];
    xj[t][0] = X[j * 3 + 0];
    xj[t][1] = X[j * 3 + 1];
    xj[t][2] = X[j * 3 + 2];
  }
  __syncthreads();

  float w[6];
  #pragma unroll
  for (int c = 0; c < 6; ++c) w[c] = W1[c * HIDC + t];
  const float bb  = b1[t];
  const float xi0 = xi[0], xi1 = xi[1], xi2 = xi[2];
  const float base = bb + xi0 * w[0] + xi1 * w[1] + xi2 * w[2];
  #pragma unroll
  for (int e = 0; e < KK1; ++e) {
    float v = base + (xj[e][0] - xi0) * w[3] + (xj[e][1] - xi1) * w[4] + (xj[e][2] - xi2) * w[5];
    h1[e][t] = fmaxf(v, 0.f);
  }
  __syncthreads();

  float acc[KK1];
  const float b2t = b2[t];
  #pragma unroll
  for (int e = 0; e < KK1; ++e) acc[e] = b2t;
  for (int c4 = 0; c4 < HIDC / 4; ++c4) {
    float w0 = W2[(c4 * 4 + 0) * HIDC + t];
    float w1 = W2[(c4 * 4 + 1) * HIDC + t];
    float w2 = W2[(c4 * 4 + 2) * HIDC + t];
    float w3 = W2[(c4 * 4 + 3) * HIDC + t];
    #pragma unroll
    for (int e = 0; e < KK1; ++e) {
      float4 hv = *reinterpret_cast<const float4*>(&h1[e][c4 * 4]);
      acc[e] += hv.x * w0 + hv.y * w1 + hv.z * w2 + hv.w * w3;
    }
  }
  float m = -INFINITY;
  #pragma unroll
  for (int e = 0; e < KK1; ++e) m = fmaxf(m, acc[e]);
  H[(size_t)i * HIDC + t] = m;
}

// ---------------------------------------------------------------- EdgeConv 2
__global__ __launch_bounds__(256) void edgeconv2_kernel(
        const float* __restrict__ H, const int* __restrict__ knn,
        const float* __restrict__ W1, const float* __restrict__ b1,
        const float* __restrict__ W2, const float* __restrict__ b2,
        float* __restrict__ Out) {
  const int i = blockIdx.x;
  const int t = threadIdx.x;
  __shared__ float hi[HIDC];
  __shared__ float hj[KK2][HIDC];
  __shared__ float g1[KK2][OUTC2];

  if (t < HIDC) hi[t] = H[(size_t)i * HIDC + t];
  for (int u = t; u < KK2 * HIDC; u += 256) {
    int e = u >> 7, c = u & 127;
    hj[e][c] = H[(size_t)knn[i * KK2 + e] * HIDC + c];
  }
  __syncthreads();

  float acc[KK2];
  const float b1t = b1[t];
  #pragma unroll
  for (int e = 0; e < KK2; ++e) acc[e] = b1t;
  for (int c4 = 0; c4 < HIDC / 4; ++c4) {
    float wl[4], wh[4];
    #pragma unroll
    for (int q = 0; q < 4; ++q) {
      wl[q] = W1[(c4 * 4 + q) * OUTC2 + t];
      wh[q] = W1[(HIDC + c4 * 4 + q) * OUTC2 + t];
    }
    float4 hv = *reinterpret_cast<const float4*>(&hi[c4 * 4]);
    #pragma unroll
    for (int e = 0; e < KK2; ++e) {
      float4 jv = *reinterpret_cast<const float4*>(&hj[e][c4 * 4]);
      acc[e] += (hv.x * wl[0] + (jv.x - hv.x) * wh[0])
              + (hv.y * wl[1] + (jv.y - hv.y) * wh[1])
              + (hv.z * wl[2] + (jv.z - hv.z) * wh[2])
              + (hv.w * wl[3] + (jv.w - hv.w) * wh[3]);
    }
  }
  #pragma unroll
  for (int e = 0; e < KK2; ++e) g1[e][t] = fmaxf(acc[e], 0.f);
  __syncthreads();

  float acc2[KK2];
  const float b2t = b2[t];
  #pragma unroll
  for (int e = 0; e < KK2; ++e) acc2[e] = b2t;
  for (int c4 = 0; c4 < OUTC2 / 4; ++c4) {
    float w0 = W2[(c4 * 4 + 0) * OUTC2 + t];
    float w1 = W2[(c4 * 4 + 1) * OUTC2 + t];
    float w2 = W2[(c4 * 4 + 2) * OUTC2 + t];
    float w3 = W2[(c4 * 4 + 3) * OUTC2 + t];
    #pragma unroll
    for (int e = 0; e < KK2; ++e) {
      float4 gv = *reinterpret_cast<const float4*>(&g1[e][c4 * 4]);
      acc2[e] += gv.x * w0 + gv.y * w1 + gv.z * w2 + gv.w * w3;
    }
  }
  float m = -INFINITY;
  #pragma unroll
  for (int e = 0; e < KK2; ++e) m = fmaxf(m, acc2[e]);
  Out[(size_t)i * OUTC2 + t] = m;
}

// ---------------------------------------------------------------- launch
extern "C" void kernel_launch(void* const* d_in, const int* in_sizes, int n_in,
                              void* d_out, int out_size, void* d_ws, size_t ws_size,
                              hipStream_t stream) {
  const float* x   = (const float*)d_in[0];
  const float* W1a = (const float*)d_in[1];
  const float* b1a = (const float*)d_in[2];
  const float* W1b = (const float*)d_in[3];
  const float* b1b = (const float*)d_in[4];
  const float* W2a = (const float*)d_in[5];
  const float* b2a = (const float*)d_in[6];
  const float* W2b = (const float*)d_in[7];
  const float* b2b = (const float*)d_in[8];
  float* out = (float*)d_out;

  float* h    = (float*)d_ws;                       // 8192*128 f = 4 MB
  float* sq2  = h + (size_t)NPTS * HIDC;            // 8192 f
  int*   idx1 = (int*)(sq2 + NPTS);                 // 8192*16 i
  int*   idx2 = idx1 + (size_t)NPTS * KK1;          // 8192*8 i
  unsigned short* Hhi = (unsigned short*)(idx2 + (size_t)NPTS * KK2);  // 2 MB
  unsigned short* Hlo = Hhi + (size_t)NPTS * HIDC;                     // 2 MB
  int* pi = (int*)(Hlo + (size_t)NPTS * HIDC);      // 8192*4*16 i = 2 MB
  // x4 aliases h's first 128KB: knn3 finishes before edgeconv1 writes h.
  float4* x4 = (float4*)h;

  pack_x_kernel<<<(NPTS + 255) / 256, 256, 0, stream>>>(x, x4);
  knn3_kernel<<<NPTS / Q1, 512, 0, stream>>>(x4, idx1);
  edgeconv1_kernel<<<NPTS, 128, 0, stream>>>(x, idx1, W1a, b1a, W1b, b1b, h);
  h_prep_kernel<<<NPTS, 128, 0, stream>>>(h, Hhi, Hlo, sq2);
  knn128_mfma_kernel<<<(NPTS / 32) * JSPLIT, 256, 0, stream>>>(Hhi, Hlo, sq2, pi);
  knn_rescore_kernel<<<NPTS / 4, 256, 0, stream>>>(h, sq2, pi, idx2);
  edgeconv2_kernel<<<NPTS, 256, 0, stream>>>(h, idx2, W2a, b2a, W2b, b2b, out);
}

// Round 5
// 1084.361 us; speedup vs baseline: 4.7207x; 1.4918x over previous
//
#include <hip/hip_runtime.h>
#include <math.h>

constexpr int NPTS  = 8192;
constexpr int HIDC  = 128;
constexpr int OUTC2 = 256;
constexpr int KK1   = 16;
constexpr int KK2   = 8;

typedef __attribute__((ext_vector_type(8))) short short8;
typedef __attribute__((ext_vector_type(4))) float f32x4;
typedef __attribute__((ext_vector_type(4))) int   i32x4;

__device__ __forceinline__ f32x4 mfma16(short8 a, short8 b, f32x4 c) {
  return __builtin_amdgcn_mfma_f32_16x16x32_bf16(a, b, c, 0, 0, 0);
}

// pure strict-< insert. For a per-lane stream with ascending j this is
// EXACTLY lexicographic (d, idx) top-K semantics (ties keep earlier=smaller j).
template <int K>
__device__ __forceinline__ void ins_f(float (&kf)[K], int (&ki)[K], float v, int j) {
  if (v < kf[K - 1]) {
    kf[K - 1] = v; ki[K - 1] = j;
    #pragma unroll
    for (int p = K - 1; p > 0; --p) {
      bool sw = kf[p] < kf[p - 1];
      float tf = kf[p - 1]; int ti = ki[p - 1];
      kf[p - 1] = sw ? kf[p] : tf;  ki[p - 1] = sw ? ki[p] : ti;
      kf[p]     = sw ? tf : kf[p];  ki[p]     = sw ? ti : ki[p];
    }
  }
}

// lexicographic (d, idx) insert — for merging lists whose idx order is mixed.
template <int K>
__device__ __forceinline__ void ins_lex(float (&kf)[K], int (&ki)[K], float v, int j) {
  bool ins = (v < kf[K - 1]) || (v == kf[K - 1] && j < ki[K - 1]);
  if (ins) {
    kf[K - 1] = v; ki[K - 1] = j;
    #pragma unroll
    for (int p = K - 1; p > 0; --p) {
      float fa = kf[p - 1], fb = kf[p];
      int   ia = ki[p - 1], ib = ki[p];
      bool sw = (fb < fa) || (fb == fa && ib < ia);
      kf[p - 1] = sw ? fb : fa; ki[p - 1] = sw ? ib : ia;
      kf[p]     = sw ? fa : fb; ki[p]     = sw ? ia : ib;
    }
  }
}

__device__ __forceinline__ unsigned short bf16_rn(float x) {
  unsigned int u = __float_as_uint(x);
  unsigned int r = u + 0x7fffu + ((u >> 16) & 1u);
  return (unsigned short)(r >> 16);
}

// ---------------------------------------------------------------- pack x
__global__ void pack_x_kernel(const float* __restrict__ x, float4* __restrict__ x4) {
  int i = blockIdx.x * blockDim.x + threadIdx.x;
  if (i < NPTS) {
    float a = x[3 * i], b = x[3 * i + 1], c = x[3 * i + 2];
    x4[i] = make_float4(a, b, c, a * a + b * b + c * c);
  }
}

// ---------------------------------------------------------------- KNN1 (C=3, K=16) — exact
// 256 thr, 16 queries/block, D-tile staging, per-thread pure-< top-16
// (exact superset), in-kernel 16-list heads-argmin merge (exact lex).
constexpr int Q3  = 16, JT3 = 256, NC3 = NPTS / JT3;

__global__ __launch_bounds__(256) void knn3_kernel(const float4* __restrict__ X4,
                                                   int* __restrict__ idx_out) {
  __shared__ char smem_raw[35072];
  float* Dt = (float*)smem_raw;                 // [16][260]
  float* lf = (float*)smem_raw;                 // [16*16][17] overlay (after scan)
  int*   li = (int*)(smem_raw + 17408);
  const int tid  = threadIdx.x;
  const int lane = tid & 63;
  const int wv   = __builtin_amdgcn_readfirstlane(tid >> 6);
  const int qg0  = blockIdx.x * Q3 + 4 * wv;

  const float4 qv0 = X4[qg0], qv1 = X4[qg0 + 1], qv2 = X4[qg0 + 2], qv3 = X4[qg0 + 3];
  float qx[4] = {qv0.x, qv1.x, qv2.x, qv3.x};
  float qy[4] = {qv0.y, qv1.y, qv2.y, qv3.y};
  float qz[4] = {qv0.z, qv1.z, qv2.z, qv3.z};
  float qw[4] = {qv0.w, qv1.w, qv2.w, qv3.w};

  float kf[KK1]; int ki[KK1];
  #pragma unroll
  for (int k = 0; k < KK1; ++k) { kf[k] = INFINITY; ki[k] = 0x7fffffff; }
  const int sq_q = tid >> 4;   // 0..15 query
  const int sq_p = tid & 15;   // 0..15 part

  for (int ch = 0; ch < NC3; ++ch) {
    const int j0 = ch * JT3;
    float4 jv[4];
    #pragma unroll
    for (int ji = 0; ji < 4; ++ji) jv[ji] = X4[j0 + 4 * lane + ji];
    #pragma unroll
    for (int qi = 0; qi < 4; ++qi) {
      float d[4];
      #pragma unroll
      for (int ji = 0; ji < 4; ++ji) {
        float dot = qx[qi] * jv[ji].x + qy[qi] * jv[ji].y + qz[qi] * jv[ji].z;
        d[ji] = qw[qi] + jv[ji].w - 2.f * dot;
        if (j0 + 4 * lane + ji == qg0 + qi) d[ji] = INFINITY;
      }
      *(float4*)&Dt[(4 * wv + qi) * 260 + 4 * lane] = make_float4(d[0], d[1], d[2], d[3]);
    }
    __syncthreads();
    #pragma unroll
    for (int s4 = 0; s4 < 4; ++s4) {
      f32x4 dv = *(const f32x4*)&Dt[sq_q * 260 + sq_p * 16 + s4 * 4];
      #pragma unroll
      for (int t = 0; t < 4; ++t)
        ins_f<KK1>(kf, ki, dv[t], j0 + sq_p * 16 + s4 * 4 + t);
    }
    __syncthreads();
  }

  // dump sorted per-thread lists (overlay Dt region — scan done)
  #pragma unroll
  for (int k = 0; k < KK1; ++k) {
    lf[(sq_q * 16 + sq_p) * 17 + k] = kf[k];
    li[(sq_q * 16 + sq_p) * 17 + k] = ki[k];
  }
  __syncthreads();

  // heads-argmin merge: 16-lane group per query, 4 queries per wave
  const int g    = lane >> 4;           // 0..3
  const int q_l  = wv * 4 + g;          // 0..15 local query
  const int part = lane & 15;
  int ptr = 0;
  float hv = lf[(q_l * 16 + part) * 17];
  int   hj = li[(q_l * 16 + part) * 17];
  const int qg = blockIdx.x * Q3 + q_l;
  #pragma unroll
  for (int k = 0; k < KK1; ++k) {
    float md = hv; int mi = hj;
    #pragma unroll
    for (int m = 1; m <= 8; m <<= 1) {
      float od = __shfl_xor(md, m, 64);
      int   oi = __shfl_xor(mi, m, 64);
      if (od < md || (od == md && oi < mi)) { md = od; mi = oi; }
    }
    if (part == k) idx_out[qg * KK1 + k] = mi;
    bool win = (hv == md) && (hj == mi);
    if (win) {
      ++ptr;
      hv = lf[(q_l * 16 + part) * 17 + ptr];
      hj = li[(q_l * 16 + part) * 17 + ptr];
    }
  }
}

// ---------------------------------------------------------------- EdgeConv 1
// block 256 = 4 waves; wave = 2 points (half-wave per point); thread: 4 channels.
// Fuses h -> (H fp32, Hhi/Hlo bf16 split, sqnorm).
__global__ __launch_bounds__(256) void edgeconv1_kernel(
    const float* __restrict__ X, const int* __restrict__ knn,
    const float* __restrict__ W1, const float* __restrict__ b1,
    const float* __restrict__ W2, const float* __restrict__ b2,
    float* __restrict__ H, unsigned short* __restrict__ Hhi,
    unsigned short* __restrict__ Hlo, float* __restrict__ SQ2) {
  __shared__ float h1[8][KK1][HIDC];   // 64 KB
  __shared__ float xjs[8][KK1][3];
  __shared__ float xis[8][3];
  const int tid  = threadIdx.x;
  const int lane = tid & 63;
  const int wv   = __builtin_amdgcn_readfirstlane(tid >> 6);
  const int half = lane >> 5;
  const int hl   = lane & 31;
  const int lp   = wv * 2 + half;            // local point 0..7
  const int p    = blockIdx.x * 8 + lp;
  const int ch0  = hl * 4;

  if (hl < KK1) {
    int j = knn[p * KK1 + hl];
    xjs[lp][hl][0] = X[3 * j]; xjs[lp][hl][1] = X[3 * j + 1]; xjs[lp][hl][2] = X[3 * j + 2];
  } else if (hl < KK1 + 3) {
    xis[lp][hl - KK1] = X[3 * p + hl - KK1];
  }
  __syncthreads();

  // stage 1
  f32x4 w1r[6];
  #pragma unroll
  for (int c = 0; c < 6; ++c) w1r[c] = *(const f32x4*)&W1[c * HIDC + ch0];
  f32x4 b1v = *(const f32x4*)&b1[ch0];
  const float xi0 = xis[lp][0], xi1 = xis[lp][1], xi2 = xis[lp][2];
  f32x4 base;
  #pragma unroll
  for (int c = 0; c < 4; ++c)
    base[c] = b1v[c] + xi0 * w1r[0][c] + xi1 * w1r[1][c] + xi2 * w1r[2][c];
  #pragma unroll
  for (int e = 0; e < KK1; ++e) {
    float dx = xjs[lp][e][0] - xi0, dy = xjs[lp][e][1] - xi1, dz = xjs[lp][e][2] - xi2;
    f32x4 v;
    #pragma unroll
    for (int c = 0; c < 4; ++c)
      v[c] = fmaxf(base[c] + dx * w1r[3][c] + dy * w1r[4][c] + dz * w1r[5][c], 0.f);
    *(f32x4*)&h1[lp][e][ch0] = v;
  }
  __syncthreads();

  // stage 2: thread accumulates 16 edges x 4 channels
  float acc[KK1][4];
  #pragma unroll
  for (int e = 0; e < KK1; ++e)
    #pragma unroll
    for (int c = 0; c < 4; ++c) acc[e][c] = 0.f;
  for (int c4 = 0; c4 < HIDC / 4; ++c4) {
    f32x4 w2r[4];
    #pragma unroll
    for (int cc = 0; cc < 4; ++cc)
      w2r[cc] = *(const f32x4*)&W2[(c4 * 4 + cc) * HIDC + ch0];
    #pragma unroll
    for (int e = 0; e < KK1; ++e) {
      f32x4 hv = *(const f32x4*)&h1[lp][e][c4 * 4];
      #pragma unroll
      for (int cc = 0; cc < 4; ++cc)
        #pragma unroll
        for (int c = 0; c < 4; ++c) acc[e][c] += hv[cc] * w2r[cc][c];
    }
  }
  f32x4 b2v = *(const f32x4*)&b2[ch0];
  f32x4 outv;
  #pragma unroll
  for (int c = 0; c < 4; ++c) {
    float m = -INFINITY;
    #pragma unroll
    for (int e = 0; e < KK1; ++e) m = fmaxf(m, acc[e][c]);
    outv[c] = m + b2v[c];
  }
  *(f32x4*)&H[(size_t)p * HIDC + ch0] = outv;

  // bf16 hi/lo split
  unsigned short hb[4], lb[4];
  #pragma unroll
  for (int c = 0; c < 4; ++c) {
    hb[c] = bf16_rn(outv[c]);
    float fh = __uint_as_float(((unsigned int)hb[c]) << 16);
    lb[c] = bf16_rn(outv[c] - fh);
  }
  *(ushort4*)&Hhi[(size_t)p * HIDC + ch0] = make_ushort4(hb[0], hb[1], hb[2], hb[3]);
  *(ushort4*)&Hlo[(size_t)p * HIDC + ch0] = make_ushort4(lb[0], lb[1], lb[2], lb[3]);

  // sqnorm reduce across the 32-lane half
  float s = outv[0]*outv[0] + outv[1]*outv[1] + outv[2]*outv[2] + outv[3]*outv[3];
  #pragma unroll
  for (int m = 1; m <= 16; m <<= 1) s += __shfl_xor(s, m, 64);
  if (hl == 0) SQ2[p] = s;
}

// ---------------------------------------------------------------- KNN2 filter (MFMA bf16x2, 3 terms)
// 1024 blocks x 256 thr, no LDS. Block = 64 queries x 1/8 of j-space.
// Per lane: top-8 (strict-<) of its 256-row stream -> provable superset.
constexpr int JSPLIT = 8;
constexpr int JPB2   = NPTS / JSPLIT;   // 1024 rows
constexpr int NT2    = JPB2 / 16;       // 64 tiles
constexpr int CPQ    = JSPLIT * 4 * 8;  // 256 candidates per query

__global__ __launch_bounds__(256) void knn128_filter_kernel(
    const unsigned short* __restrict__ Hhi, const unsigned short* __restrict__ Hlo,
    const float* __restrict__ SQ, int* __restrict__ pi2) {
  const int tid  = threadIdx.x;
  const int lane = tid & 63;
  const int wv   = __builtin_amdgcn_readfirstlane(tid >> 6);
  const int qb   = blockIdx.x >> 3;
  const int js   = blockIdx.x & 7;
  const int col  = lane & 15;
  const int kg   = lane >> 4;
  const int qg   = qb * 64 + wv * 16 + col;

  short8 qhi[4], qlo[4];
  #pragma unroll
  for (int s = 0; s < 4; ++s) {
    const size_t o = (size_t)qg * HIDC + s * 32 + kg * 8;
    qhi[s] = *reinterpret_cast<const short8*>(Hhi + o);
    qlo[s] = *reinterpret_cast<const short8*>(Hlo + o);
  }
  const float sqq = SQ[qg];

  float kf[KK2]; int ki[KK2];
  #pragma unroll
  for (int k = 0; k < KK2; ++k) { kf[k] = INFINITY; ki[k] = 0x7fffffff; }

  const int jbase = js * JPB2;
  for (int it = 0; it < NT2; ++it) {
    const int jb = jbase + it * 16;
    const int arow = jb + col;
    short8 ahi[4], alo[4];
    #pragma unroll
    for (int s = 0; s < 4; ++s) {
      const size_t oa = (size_t)arow * HIDC + s * 32 + kg * 8;
      ahi[s] = *reinterpret_cast<const short8*>(Hhi + oa);
      alo[s] = *reinterpret_cast<const short8*>(Hlo + oa);
    }
    f32x4 sqjv = *reinterpret_cast<const f32x4*>(SQ + jb + kg * 4);

    f32x4 acc = {0.f, 0.f, 0.f, 0.f};
    #pragma unroll
    for (int s = 0; s < 4; ++s) {
      acc = mfma16(ahi[s], qhi[s], acc);
      acc = mfma16(ahi[s], qlo[s], acc);
      acc = mfma16(alo[s], qhi[s], acc);
    }
    // D: col=lane&15 (query), row=kg*4+reg (m89/m91-verified; same as R4)
    #pragma unroll
    for (int r = 0; r < 4; ++r) {
      const int jg = jb + kg * 4 + r;
      float d = sqq + sqjv[r] - 2.f * acc[r];
      if (jg == qg) d = INFINITY;
      ins_f<KK2>(kf, ki, d, jg);
    }
  }
  const size_t base = (size_t)qg * CPQ + js * 32 + kg * 8;
  #pragma unroll
  for (int k = 0; k < KK2; ++k) pi2[base + k] = ki[k];
}

// ---------------------------------------------------------------- exact fp32 rescore (256 cands)
__global__ __launch_bounds__(256) void knn_rescore_kernel(
    const float* __restrict__ H, const float* __restrict__ SQ,
    const int* __restrict__ pi2, int* __restrict__ idx_out) {
  const int tid  = threadIdx.x;
  const int wv   = tid >> 6;
  const int lane = tid & 63;
  const int q0   = blockIdx.x * 4;
  const int q    = q0 + wv;
  __shared__ float qrow[4][HIDC];
  #pragma unroll
  for (int u = tid; u < 4 * HIDC; u += 256)
    qrow[u >> 7][u & 127] = H[(size_t)(q0 + (u >> 7)) * HIDC + (u & 127)];
  __syncthreads();

  i32x4 cand = *reinterpret_cast<const i32x4*>(&pi2[(size_t)q * CPQ + lane * 4]);
  float acc[4] = {0.f, 0.f, 0.f, 0.f};
  for (int c4 = 0; c4 < HIDC / 4; ++c4) {
    f32x4 qv = *(const f32x4*)&qrow[wv][c4 * 4];
    #pragma unroll
    for (int j = 0; j < 4; ++j) {
      f32x4 cv = *(const f32x4*)&H[(size_t)cand[j] * HIDC + c4 * 4];
      acc[j] += qv[0] * cv[0] + qv[1] * cv[1] + qv[2] * cv[2] + qv[3] * cv[3];
    }
  }
  const float sqq = SQ[q];
  float kf[KK2]; int ki[KK2];
  #pragma unroll
  for (int k = 0; k < KK2; ++k) { kf[k] = INFINITY; ki[k] = 0x7fffffff; }
  #pragma unroll
  for (int j = 0; j < 4; ++j) {
    float d = sqq + SQ[cand[j]] - 2.f * acc[j];
    if (cand[j] == q) d = INFINITY;
    ins_lex<KK2>(kf, ki, d, cand[j]);
  }
  #pragma unroll
  for (int dlt = 1; dlt <= 32; dlt <<= 1) {
    float of[KK2]; int oi[KK2];
    #pragma unroll
    for (int k = 0; k < KK2; ++k) { of[k] = __shfl_xor(kf[k], dlt, 64); oi[k] = __shfl_xor(ki[k], dlt, 64); }
    #pragma unroll
    for (int k = 0; k < KK2; ++k) ins_lex<KK2>(kf, ki, of[k], oi[k]);
  }
  if (lane == 0) {
    #pragma unroll
    for (int k = 0; k < KK2; ++k) idx_out[(size_t)q * KK2 + k] = ki[k];
  }
}

// ---------------------------------------------------------------- EdgeConv 2
// block 256 = 4 waves; wave = 1 point; thread: 4 output channels.
__global__ __launch_bounds__(256) void edgeconv2_kernel(
    const float* __restrict__ H, const int* __restrict__ knn,
    const float* __restrict__ W1, const float* __restrict__ b1,
    const float* __restrict__ W2, const float* __restrict__ b2,
    float* __restrict__ Out) {
  __shared__ float hi[4][HIDC];
  __shared__ float hj[4][KK2][HIDC];
  __shared__ float g1[4][KK2][OUTC2];
  const int tid  = threadIdx.x;
  const int lane = tid & 63;
  const int wv   = __builtin_amdgcn_readfirstlane(tid >> 6);
  const int p    = blockIdx.x * 4 + wv;
  const int ch0  = lane * 4;

  if (lane < 32) *(f32x4*)&hi[wv][lane * 4] = *(const f32x4*)&H[(size_t)p * HIDC + lane * 4];
  #pragma unroll
  for (int r = 0; r < 4; ++r) {
    int u = r * 64 + lane;
    int e = u >> 5, cc = (u & 31) * 4;
    int j = knn[p * KK2 + e];
    *(f32x4*)&hj[wv][e][cc] = *(const f32x4*)&H[(size_t)j * HIDC + cc];
  }
  __syncthreads();

  // stage 1: g1[e][ch] = relu(hi@Wl + (hj-hi)@Wh + b1)
  f32x4 bacc = {0.f, 0.f, 0.f, 0.f};
  float acc[KK2][4];
  #pragma unroll
  for (int e = 0; e < KK2; ++e)
    #pragma unroll
    for (int c = 0; c < 4; ++c) acc[e][c] = 0.f;
  for (int c4 = 0; c4 < HIDC / 4; ++c4) {
    f32x4 hv = *(const f32x4*)&hi[wv][c4 * 4];
    f32x4 wl[4], wh[4];
    #pragma unroll
    for (int cc = 0; cc < 4; ++cc) {
      wl[cc] = *(const f32x4*)&W1[(size_t)(c4 * 4 + cc) * OUTC2 + ch0];
      wh[cc] = *(const f32x4*)&W1[(size_t)(HIDC + c4 * 4 + cc) * OUTC2 + ch0];
    }
    #pragma unroll
    for (int cc = 0; cc < 4; ++cc)
      #pragma unroll
      for (int c = 0; c < 4; ++c) bacc[c] += hv[cc] * wl[cc][c];
    #pragma unroll
    for (int e = 0; e < KK2; ++e) {
      f32x4 jv = *(const f32x4*)&hj[wv][e][c4 * 4];
      f32x4 dv;
      #pragma unroll
      for (int cc = 0; cc < 4; ++cc) dv[cc] = jv[cc] - hv[cc];
      #pragma unroll
      for (int cc = 0; cc < 4; ++cc)
        #pragma unroll
        for (int c = 0; c < 4; ++c) acc[e][c] += dv[cc] * wh[cc][c];
    }
  }
  f32x4 b1v = *(const f32x4*)&b1[ch0];
  #pragma unroll
  for (int e = 0; e < KK2; ++e) {
    f32x4 g;
    #pragma unroll
    for (int c = 0; c < 4; ++c) g[c] = fmaxf(acc[e][c] + bacc[c] + b1v[c], 0.f);
    *(f32x4*)&g1[wv][e][ch0] = g;
  }
  __syncthreads();

  // stage 2: out[ch] = max_e (g1[e] @ W2 + b2)
  float acc2[KK2][4];
  #pragma unroll
  for (int e = 0; e < KK2; ++e)
    #pragma unroll
    for (int c = 0; c < 4; ++c) acc2[e][c] = 0.f;
  for (int c4 = 0; c4 < OUTC2 / 4; ++c4) {
    f32x4 w2[4];
    #pragma unroll
    for (int cc = 0; cc < 4; ++cc)
      w2[cc] = *(const f32x4*)&W2[(size_t)(c4 * 4 + cc) * OUTC2 + ch0];
    #pragma unroll
    for (int e = 0; e < KK2; ++e) {
      f32x4 gv = *(const f32x4*)&g1[wv][e][c4 * 4];
      #pragma unroll
      for (int cc = 0; cc < 4; ++cc)
        #pragma unroll
        for (int c = 0; c < 4; ++c) acc2[e][c] += gv[cc] * w2[cc][c];
    }
  }
  f32x4 b2v = *(const f32x4*)&b2[ch0];
  f32x4 outv;
  #pragma unroll
  for (int c = 0; c < 4; ++c) {
    float m = -INFINITY;
    #pragma unroll
    for (int e = 0; e < KK2; ++e) m = fmaxf(m, acc2[e][c]);
    outv[c] = m + b2v[c];
  }
  *(f32x4*)&Out[(size_t)p * OUTC2 + ch0] = outv;
}

// ---------------------------------------------------------------- launch
extern "C" void kernel_launch(void* const* d_in, const int* in_sizes, int n_in,
                              void* d_out, int out_size, void* d_ws, size_t ws_size,
                              hipStream_t stream) {
  const float* x   = (const float*)d_in[0];
  const float* W1a = (const float*)d_in[1];
  const float* b1a = (const float*)d_in[2];
  const float* W1b = (const float*)d_in[3];
  const float* b1b = (const float*)d_in[4];
  const float* W2a = (const float*)d_in[5];
  const float* b2a = (const float*)d_in[6];
  const float* W2b = (const float*)d_in[7];
  const float* b2b = (const float*)d_in[8];
  float* out = (float*)d_out;

  float* h    = (float*)d_ws;                       // 8192*128 f = 4 MB
  float* sq2  = h + (size_t)NPTS * HIDC;            // 8192 f
  int*   idx1 = (int*)(sq2 + NPTS);                 // 8192*16
  int*   idx2 = idx1 + (size_t)NPTS * KK1;          // 8192*8
  unsigned short* Hhi = (unsigned short*)(idx2 + (size_t)NPTS * KK2);  // 2 MB
  unsigned short* Hlo = Hhi + (size_t)NPTS * HIDC;                     // 2 MB
  int* pi2 = (int*)(Hlo + (size_t)NPTS * HIDC);     // 8192*256 i = 8 MB
  // x4 aliases h's first 128KB: knn3 finishes before edgeconv1 writes h.
  float4* x4 = (float4*)h;

  pack_x_kernel<<<(NPTS + 255) / 256, 256, 0, stream>>>(x, x4);
  knn3_kernel<<<NPTS / Q3, 256, 0, stream>>>(x4, idx1);
  edgeconv1_kernel<<<NPTS / 8, 256, 0, stream>>>(x, idx1, W1a, b1a, W1b, b1b,
                                                 h, Hhi, Hlo, sq2);
  knn128_filter_kernel<<<(NPTS / 64) * JSPLIT, 256, 0, stream>>>(Hhi, Hlo, sq2, pi2);
  knn_rescore_kernel<<<NPTS / 4, 256, 0, stream>>>(h, sq2, pi2, idx2);
  edgeconv2_kernel<<<NPTS / 4, 256, 0, stream>>>(h, idx2, W2a, b2a, W2b, b2b, out);
}

// Round 6
// 899.382 us; speedup vs baseline: 5.6916x; 1.2057x over previous
//
#include <hip/hip_runtime.h>
#include <math.h>

constexpr int NPTS  = 8192;
constexpr int HIDC  = 128;
constexpr int OUTC2 = 256;
constexpr int PQC   = 512;
constexpr int KK1   = 16;
constexpr int KK2   = 8;

typedef __attribute__((ext_vector_type(8))) short short8;
typedef __attribute__((ext_vector_type(4))) float f32x4;
typedef __attribute__((ext_vector_type(4))) int   i32x4;

__device__ __forceinline__ f32x4 mfma16(short8 a, short8 b, f32x4 c) {
  return __builtin_amdgcn_mfma_f32_16x16x32_bf16(a, b, c, 0, 0, 0);
}

// pure strict-< insert (exact lex when per-lane stream has ascending j).
template <int K>
__device__ __forceinline__ void ins_f(float (&kf)[K], int (&ki)[K], float v, int j) {
  if (v < kf[K - 1]) {
    kf[K - 1] = v; ki[K - 1] = j;
    #pragma unroll
    for (int p = K - 1; p > 0; --p) {
      bool sw = kf[p] < kf[p - 1];
      float tf = kf[p - 1]; int ti = ki[p - 1];
      kf[p - 1] = sw ? kf[p] : tf;  ki[p - 1] = sw ? ki[p] : ti;
      kf[p]     = sw ? tf : kf[p];  ki[p]     = sw ? ti : ki[p];
    }
  }
}

// lexicographic (d, idx) insert — for merging lists whose idx order is mixed.
template <int K>
__device__ __forceinline__ void ins_lex(float (&kf)[K], int (&ki)[K], float v, int j) {
  bool ins = (v < kf[K - 1]) || (v == kf[K - 1] && j < ki[K - 1]);
  if (ins) {
    kf[K - 1] = v; ki[K - 1] = j;
    #pragma unroll
    for (int p = K - 1; p > 0; --p) {
      float fa = kf[p - 1], fb = kf[p];
      int   ia = ki[p - 1], ib = ki[p];
      bool sw = (fb < fa) || (fb == fa && ib < ia);
      kf[p - 1] = sw ? fb : fa; ki[p - 1] = sw ? ib : ia;
      kf[p]     = sw ? fa : fb; ki[p]     = sw ? ia : ib;
    }
  }
}

__device__ __forceinline__ unsigned short bf16_rn(float x) {
  unsigned int u = __float_as_uint(x);
  unsigned int r = u + 0x7fffu + ((u >> 16) & 1u);
  return (unsigned short)(r >> 16);
}

__device__ __forceinline__ float rdlane_f(float v, int l) {
  return __int_as_float(__builtin_amdgcn_readlane(__float_as_int(v), l));
}

// ---------------------------------------------------------------- pack x
__global__ void pack_x_kernel(const float* __restrict__ x, float4* __restrict__ x4) {
  int i = blockIdx.x * blockDim.x + threadIdx.x;
  if (i < NPTS) {
    float a = x[3 * i], b = x[3 * i + 1], c = x[3 * i + 2];
    x4[i] = make_float4(a, b, c, a * a + b * b + c * c);
  }
}

// ---------------------------------------------------------------- Wc = [Wl-Wh | Wh] for layer2 stage1
__global__ void prep_w1_kernel(const float* __restrict__ W1, float* __restrict__ Wc) {
  int idx = blockIdx.x * 256 + threadIdx.x;    // 128*512
  int k = idx >> 9, c = idx & 511;
  float wh = W1[(size_t)(HIDC + k) * OUTC2 + (c & 255)];
  Wc[idx] = (c < OUTC2) ? (W1[(size_t)k * OUTC2 + c] - wh) : wh;
}

// ---------------------------------------------------------------- KNN1 (C=3, K=16), ballot-scan
// 4 waves/block, 2 queries/wave. Distributed top-16 list: lane i of each
// 16-lane subgroup holds slot i; worst (lex-max) tracked wave-uniform.
// Common path per 64 candidates: dist + lex cmp + ballot. Insert events
// (~100/query) pay a 4-step shuffle lex-argmax reduce. Exact lex-min-16 SET
// (order-free; downstream max-pool is order-invariant).
__global__ __launch_bounds__(256) void knn3_kernel(const float4* __restrict__ X4,
                                                   int* __restrict__ idx_out) {
  const int tid  = threadIdx.x;
  const int lane = tid & 63;
  const int wv   = __builtin_amdgcn_readfirstlane(tid >> 6);
  const int half = lane >> 5;           // which query of the wave
  const int l16  = lane & 15;           // list slot
  const bool listlane = (lane & 16) == 0;
  const int q0 = (blockIdx.x * 4 + wv) * 2;

  float qx[2], qy[2], qz[2], qw[2];
  #pragma unroll
  for (int q = 0; q < 2; ++q) {
    float4 v = X4[q0 + q];
    qx[q] = v.x; qy[q] = v.y; qz[q] = v.z; qw[q] = v.w;
  }

  float kd = INFINITY; int kj = 0x7fffffff;
  float wd[2]; int wj[2], ws[2];
  #pragma unroll
  for (int q = 0; q < 2; ++q) { wd[q] = INFINITY; wj[q] = 0x7fffffff; ws[q] = 0; }

  float4 pj = X4[lane];
  for (int j0 = 0; j0 < NPTS; j0 += 64) {
    float4 pjn = pj;
    if (j0 + 64 < NPTS) pjn = X4[j0 + 64 + lane];
    const int j = j0 + lane;
    #pragma unroll
    for (int q = 0; q < 2; ++q) {
      float d = qw[q] + pj.w - 2.f * (qx[q] * pj.x + qy[q] * pj.y + qz[q] * pj.z);
      bool c = (j != q0 + q) && ((d < wd[q]) || (d == wd[q] && j < wj[q]));
      unsigned long long vote = __ballot(c);
      while (vote) {
        const int l = (int)__ffsll(vote) - 1;
        vote &= vote - 1;
        const float dv = rdlane_f(d, l);
        const int   jv = j0 + l;
        if ((dv < wd[q]) || (dv == wd[q] && jv < wj[q])) {   // recheck vs CURRENT worst
          const bool mine = (half == q) && listlane && (l16 == ws[q]);
          kd = mine ? dv : kd;
          kj = mine ? jv : kj;
          // 16-lane lex-argmax (worst) reduce; carries slot index
          float av = kd; int aj = kj; int as = l16;
          #pragma unroll
          for (int m = 1; m <= 8; m <<= 1) {
            float ov = __shfl_xor(av, m, 64);
            int   oj = __shfl_xor(aj, m, 64);
            int   os = __shfl_xor(as, m, 64);
            bool g = (ov > av) || (ov == av && oj > aj);
            av = g ? ov : av; aj = g ? oj : aj; as = g ? os : as;
          }
          wd[q] = rdlane_f(av, q * 32);
          wj[q] = __builtin_amdgcn_readlane(aj, q * 32);
          ws[q] = __builtin_amdgcn_readlane(as, q * 32);
        }
      }
    }
    pj = pjn;
  }
  if (listlane)
    idx_out[(size_t)(q0 + half) * KK1 + l16] = kj;
}

// ---------------------------------------------------------------- EdgeConv 1
// block 256 = 4 waves; wave = 2 points (half-wave per point); thread: 4 channels.
// Fuses h -> (H fp32, Hhi/Hlo bf16 split, sqnorm).  (unchanged from R5)
__global__ __launch_bounds__(256) void edgeconv1_kernel(
    const float* __restrict__ X, const int* __restrict__ knn,
    const float* __restrict__ W1, const float* __restrict__ b1,
    const float* __restrict__ W2, const float* __restrict__ b2,
    float* __restrict__ H, unsigned short* __restrict__ Hhi,
    unsigned short* __restrict__ Hlo, float* __restrict__ SQ2) {
  __shared__ float h1[8][KK1][HIDC];
  __shared__ float xjs[8][KK1][3];
  __shared__ float xis[8][3];
  const int tid  = threadIdx.x;
  const int lane = tid & 63;
  const int wv   = __builtin_amdgcn_readfirstlane(tid >> 6);
  const int half = lane >> 5;
  const int hl   = lane & 31;
  const int lp   = wv * 2 + half;
  const int p    = blockIdx.x * 8 + lp;
  const int ch0  = hl * 4;

  if (hl < KK1) {
    int j = knn[p * KK1 + hl];
    xjs[lp][hl][0] = X[3 * j]; xjs[lp][hl][1] = X[3 * j + 1]; xjs[lp][hl][2] = X[3 * j + 2];
  } else if (hl < KK1 + 3) {
    xis[lp][hl - KK1] = X[3 * p + hl - KK1];
  }
  __syncthreads();

  f32x4 w1r[6];
  #pragma unroll
  for (int c = 0; c < 6; ++c) w1r[c] = *(const f32x4*)&W1[c * HIDC + ch0];
  f32x4 b1v = *(const f32x4*)&b1[ch0];
  const float xi0 = xis[lp][0], xi1 = xis[lp][1], xi2 = xis[lp][2];
  f32x4 base;
  #pragma unroll
  for (int c = 0; c < 4; ++c)
    base[c] = b1v[c] + xi0 * w1r[0][c] + xi1 * w1r[1][c] + xi2 * w1r[2][c];
  #pragma unroll
  for (int e = 0; e < KK1; ++e) {
    float dx = xjs[lp][e][0] - xi0, dy = xjs[lp][e][1] - xi1, dz = xjs[lp][e][2] - xi2;
    f32x4 v;
    #pragma unroll
    for (int c = 0; c < 4; ++c)
      v[c] = fmaxf(base[c] + dx * w1r[3][c] + dy * w1r[4][c] + dz * w1r[5][c], 0.f);
    *(f32x4*)&h1[lp][e][ch0] = v;
  }
  __syncthreads();

  float acc[KK1][4];
  #pragma unroll
  for (int e = 0; e < KK1; ++e)
    #pragma unroll
    for (int c = 0; c < 4; ++c) acc[e][c] = 0.f;
  for (int c4 = 0; c4 < HIDC / 4; ++c4) {
    f32x4 w2r[4];
    #pragma unroll
    for (int cc = 0; cc < 4; ++cc)
      w2r[cc] = *(const f32x4*)&W2[(c4 * 4 + cc) * HIDC + ch0];
    #pragma unroll
    for (int e = 0; e < KK1; ++e) {
      f32x4 hv = *(const f32x4*)&h1[lp][e][c4 * 4];
      #pragma unroll
      for (int cc = 0; cc < 4; ++cc)
        #pragma unroll
        for (int c = 0; c < 4; ++c) acc[e][c] += hv[cc] * w2r[cc][c];
    }
  }
  f32x4 b2v = *(const f32x4*)&b2[ch0];
  f32x4 outv;
  #pragma unroll
  for (int c = 0; c < 4; ++c) {
    float m = -INFINITY;
    #pragma unroll
    for (int e = 0; e < KK1; ++e) m = fmaxf(m, acc[e][c]);
    outv[c] = m + b2v[c];
  }
  *(f32x4*)&H[(size_t)p * HIDC + ch0] = outv;

  unsigned short hb[4], lb[4];
  #pragma unroll
  for (int c = 0; c < 4; ++c) {
    hb[c] = bf16_rn(outv[c]);
    float fh = __uint_as_float(((unsigned int)hb[c]) << 16);
    lb[c] = bf16_rn(outv[c] - fh);
  }
  *(ushort4*)&Hhi[(size_t)p * HIDC + ch0] = make_ushort4(hb[0], hb[1], hb[2], hb[3]);
  *(ushort4*)&Hlo[(size_t)p * HIDC + ch0] = make_ushort4(lb[0], lb[1], lb[2], lb[3]);

  float s = outv[0]*outv[0] + outv[1]*outv[1] + outv[2]*outv[2] + outv[3]*outv[3];
  #pragma unroll
  for (int m = 1; m <= 16; m <<= 1) s += __shfl_xor(s, m, 64);
  if (hl == 0) SQ2[p] = s;
}

// ---------------------------------------------------------------- PQ = H @ Wc (+b1 on P half)
// P[i,c] = sum_k H[i,k] (Wl-Wh)[k,c] + b1[c];  Q[i,c] = sum_k H[i,k] Wh[k,c]
__global__ __launch_bounds__(256) void gemm_pq_kernel(
    const float* __restrict__ H, const float* __restrict__ Wc,
    const float* __restrict__ b1, float* __restrict__ PQ) {
  __shared__ float Hs[32][HIDC];
  const int tid = threadIdx.x;
  const int rb  = blockIdx.x >> 3;
  const int cb  = blockIdx.x & 7;
  const int col = cb * 64 + (tid & 63);
  const int rg  = tid >> 6;

  #pragma unroll
  for (int u = 0; u < 4; ++u) {
    int idx = u * 256 + tid;           // 1024 f32x4 = 32 rows x 32 vec4
    int r = idx >> 5, k4 = idx & 31;
    *(f32x4*)&Hs[r][k4 * 4] = *(const f32x4*)&H[(size_t)(rb * 32 + r) * HIDC + k4 * 4];
  }
  __syncthreads();

  float acc[8] = {};
  for (int k = 0; k < HIDC; ++k) {
    float w = Wc[(size_t)k * PQC + col];
    #pragma unroll
    for (int i = 0; i < 8; ++i) acc[i] += Hs[rg * 8 + i][k] * w;
  }
  const float bb = (col < OUTC2) ? b1[col] : 0.f;
  #pragma unroll
  for (int i = 0; i < 8; ++i)
    PQ[(size_t)(rb * 32 + rg * 8 + i) * PQC + col] = acc[i] + bb;
}

// ---------------------------------------------------------------- KNN2 filter (MFMA bf16x2, 3 terms)
constexpr int JSPLIT = 8;
constexpr int JPB2   = NPTS / JSPLIT;
constexpr int NT2    = JPB2 / 16;
constexpr int CPQ    = JSPLIT * 4 * 8;   // 256 candidates per query

__global__ __launch_bounds__(256) void knn128_filter_kernel(
    const unsigned short* __restrict__ Hhi, const unsigned short* __restrict__ Hlo,
    const float* __restrict__ SQ, int* __restrict__ pi2) {
  const int tid  = threadIdx.x;
  const int lane = tid & 63;
  const int wv   = __builtin_amdgcn_readfirstlane(tid >> 6);
  const int qb   = blockIdx.x >> 3;
  const int js   = blockIdx.x & 7;
  const int col  = lane & 15;
  const int kg   = lane >> 4;
  const int qg   = qb * 64 + wv * 16 + col;

  short8 qhi[4], qlo[4];
  #pragma unroll
  for (int s = 0; s < 4; ++s) {
    const size_t o = (size_t)qg * HIDC + s * 32 + kg * 8;
    qhi[s] = *reinterpret_cast<const short8*>(Hhi + o);
    qlo[s] = *reinterpret_cast<const short8*>(Hlo + o);
  }
  const float sqq = SQ[qg];

  float kf[KK2]; int ki[KK2];
  #pragma unroll
  for (int k = 0; k < KK2; ++k) { kf[k] = INFINITY; ki[k] = 0x7fffffff; }

  const int jbase = js * JPB2;
  for (int it = 0; it < NT2; ++it) {
    const int jb = jbase + it * 16;
    const int arow = jb + col;
    short8 ahi[4], alo[4];
    #pragma unroll
    for (int s = 0; s < 4; ++s) {
      const size_t oa = (size_t)arow * HIDC + s * 32 + kg * 8;
      ahi[s] = *reinterpret_cast<const short8*>(Hhi + oa);
      alo[s] = *reinterpret_cast<const short8*>(Hlo + oa);
    }
    f32x4 sqjv = *reinterpret_cast<const f32x4*>(SQ + jb + kg * 4);

    f32x4 acc = {0.f, 0.f, 0.f, 0.f};
    #pragma unroll
    for (int s = 0; s < 4; ++s) {
      acc = mfma16(ahi[s], qhi[s], acc);
      acc = mfma16(ahi[s], qlo[s], acc);
      acc = mfma16(alo[s], qhi[s], acc);
    }
    #pragma unroll
    for (int r = 0; r < 4; ++r) {
      const int jg = jb + kg * 4 + r;
      float d = sqq + sqjv[r] - 2.f * acc[r];
      if (jg == qg) d = INFINITY;
      ins_f<KK2>(kf, ki, d, jg);
    }
  }
  const size_t base = (size_t)qg * CPQ + js * 32 + kg * 8;
  #pragma unroll
  for (int k = 0; k < KK2; ++k) pi2[base + k] = ki[k];
}

// ---------------------------------------------------------------- exact fp32 rescore (256 cands)
__global__ __launch_bounds__(256) void knn_rescore_kernel(
    const float* __restrict__ H, const float* __restrict__ SQ,
    const int* __restrict__ pi2, int* __restrict__ idx_out) {
  const int tid  = threadIdx.x;
  const int wv   = tid >> 6;
  const int lane = tid & 63;
  const int q0   = blockIdx.x * 4;
  const int q    = q0 + wv;
  __shared__ float qrow[4][HIDC];
  #pragma unroll
  for (int u = tid; u < 4 * HIDC; u += 256)
    qrow[u >> 7][u & 127] = H[(size_t)(q0 + (u >> 7)) * HIDC + (u & 127)];
  __syncthreads();

  i32x4 cand = *reinterpret_cast<const i32x4*>(&pi2[(size_t)q * CPQ + lane * 4]);
  float acc[4] = {0.f, 0.f, 0.f, 0.f};
  for (int c4 = 0; c4 < HIDC / 4; ++c4) {
    f32x4 qv = *(const f32x4*)&qrow[wv][c4 * 4];
    #pragma unroll
    for (int j = 0; j < 4; ++j) {
      f32x4 cv = *(const f32x4*)&H[(size_t)cand[j] * HIDC + c4 * 4];
      acc[j] += qv[0] * cv[0] + qv[1] * cv[1] + qv[2] * cv[2] + qv[3] * cv[3];
    }
  }
  const float sqq = SQ[q];
  float kf[KK2]; int ki[KK2];
  #pragma unroll
  for (int k = 0; k < KK2; ++k) { kf[k] = INFINITY; ki[k] = 0x7fffffff; }
  #pragma unroll
  for (int j = 0; j < 4; ++j) {
    float d = sqq + SQ[cand[j]] - 2.f * acc[j];
    if (cand[j] == q) d = INFINITY;
    ins_lex<KK2>(kf, ki, d, cand[j]);
  }
  #pragma unroll
  for (int dlt = 1; dlt <= 32; dlt <<= 1) {
    float of[KK2]; int oi[KK2];
    #pragma unroll
    for (int k = 0; k < KK2; ++k) { of[k] = __shfl_xor(kf[k], dlt, 64); oi[k] = __shfl_xor(ki[k], dlt, 64); }
    #pragma unroll
    for (int k = 0; k < KK2; ++k) ins_lex<KK2>(kf, ki, of[k], oi[k]);
  }
  if (lane == 0) {
    #pragma unroll
    for (int k = 0; k < KK2; ++k) idx_out[(size_t)q * KK2 + k] = ki[k];
  }
}

// ---------------------------------------------------------------- EdgeConv 2
// stage1 = relu(P[i] + Q[j]) from PQ; stage2 with block-shared W2 LDS chunks.
// block 256 = 4 waves; wave = 1 point; thread: 4 output channels.
__global__ __launch_bounds__(256) void edgeconv2_kernel(
    const float* __restrict__ PQ, const int* __restrict__ knn,
    const float* __restrict__ W2, const float* __restrict__ b2,
    float* __restrict__ Out) {
  __shared__ float g1[4][KK2][OUTC2];   // 32 KB
  __shared__ float w2s[2][8][OUTC2];    // 16 KB
  const int tid  = threadIdx.x;
  const int lane = tid & 63;
  const int wv   = __builtin_amdgcn_readfirstlane(tid >> 6);
  const int p    = blockIdx.x * 4 + wv;
  const int ch0  = lane * 4;

  // stage 1
  f32x4 pv = *(const f32x4*)&PQ[(size_t)p * PQC + ch0];
  #pragma unroll
  for (int e = 0; e < KK2; ++e) {
    int j = knn[p * KK2 + e];
    f32x4 qv = *(const f32x4*)&PQ[(size_t)j * PQC + OUTC2 + ch0];
    f32x4 g;
    #pragma unroll
    for (int c = 0; c < 4; ++c) g[c] = fmaxf(pv[c] + qv[c], 0.f);
    *(f32x4*)&g1[wv][e][ch0] = g;
  }

  // stage W2 rows 0..7
  {
    int r = tid >> 5, c0 = (tid & 31) * 8;
    *(f32x4*)&w2s[0][r][c0]     = *(const f32x4*)&W2[(size_t)r * OUTC2 + c0];
    *(f32x4*)&w2s[0][r][c0 + 4] = *(const f32x4*)&W2[(size_t)r * OUTC2 + c0 + 4];
  }
  __syncthreads();

  float acc2[KK2][4];
  #pragma unroll
  for (int e = 0; e < KK2; ++e)
    #pragma unroll
    for (int c = 0; c < 4; ++c) acc2[e][c] = 0.f;

  for (int c8 = 0; c8 < OUTC2 / 8; ++c8) {
    const int cur = c8 & 1;
    if (c8 + 1 < OUTC2 / 8) {
      int r = tid >> 5, c0 = (tid & 31) * 8;
      int gr = (c8 + 1) * 8 + r;
      *(f32x4*)&w2s[cur ^ 1][r][c0]     = *(const f32x4*)&W2[(size_t)gr * OUTC2 + c0];
      *(f32x4*)&w2s[cur ^ 1][r][c0 + 4] = *(const f32x4*)&W2[(size_t)gr * OUTC2 + c0 + 4];
    }
    f32x4 wreg[8];
    #pragma unroll
    for (int cc = 0; cc < 8; ++cc) wreg[cc] = *(const f32x4*)&w2s[cur][cc][ch0];
    #pragma unroll
    for (int e = 0; e < KK2; ++e) {
      f32x4 gv0 = *(const f32x4*)&g1[wv][e][c8 * 8];
      f32x4 gv1 = *(const f32x4*)&g1[wv][e][c8 * 8 + 4];
      #pragma unroll
      for (int cc = 0; cc < 4; ++cc)
        #pragma unroll
        for (int c = 0; c < 4; ++c) acc2[e][c] += gv0[cc] * wreg[cc][c];
      #pragma unroll
      for (int cc = 0; cc < 4; ++cc)
        #pragma unroll
        for (int c = 0; c < 4; ++c) acc2[e][c] += gv1[cc] * wreg[4 + cc][c];
    }
    __syncthreads();
  }

  f32x4 b2v = *(const f32x4*)&b2[ch0];
  f32x4 outv;
  #pragma unroll
  for (int c = 0; c < 4; ++c) {
    float m = -INFINITY;
    #pragma unroll
    for (int e = 0; e < KK2; ++e) m = fmaxf(m, acc2[e][c]);
    outv[c] = m + b2v[c];
  }
  *(f32x4*)&Out[(size_t)p * OUTC2 + ch0] = outv;
}

// ---------------------------------------------------------------- launch
extern "C" void kernel_launch(void* const* d_in, const int* in_sizes, int n_in,
                              void* d_out, int out_size, void* d_ws, size_t ws_size,
                              hipStream_t stream) {
  const float* x   = (const float*)d_in[0];
  const float* W1a = (const float*)d_in[1];
  const float* b1a = (const float*)d_in[2];
  const float* W1b = (const float*)d_in[3];
  const float* b1b = (const float*)d_in[4];
  const float* W2a = (const float*)d_in[5];
  const float* b2a = (const float*)d_in[6];
  const float* W2b = (const float*)d_in[7];
  const float* b2b = (const float*)d_in[8];
  float* out = (float*)d_out;

  float* h    = (float*)d_ws;                       // 4 MB
  float* sq2  = h + (size_t)NPTS * HIDC;
  int*   idx1 = (int*)(sq2 + NPTS);
  int*   idx2 = idx1 + (size_t)NPTS * KK1;
  unsigned short* Hhi = (unsigned short*)(idx2 + (size_t)NPTS * KK2);  // 2 MB
  unsigned short* Hlo = Hhi + (size_t)NPTS * HIDC;                     // 2 MB
  int*   pi2  = (int*)(Hlo + (size_t)NPTS * HIDC);  // 8 MB
  float* Wc   = (float*)(pi2 + (size_t)NPTS * CPQ); // 256 KB
  float* PQ   = Wc + (size_t)HIDC * PQC;            // 16 MB
  // x4 aliases h's first 128KB: knn3 finishes before edgeconv1 writes h.
  float4* x4 = (float4*)h;

  pack_x_kernel<<<(NPTS + 255) / 256, 256, 0, stream>>>(x, x4);
  prep_w1_kernel<<<(HIDC * PQC) / 256, 256, 0, stream>>>(W2a, Wc);
  knn3_kernel<<<NPTS / 8, 256, 0, stream>>>(x4, idx1);
  edgeconv1_kernel<<<NPTS / 8, 256, 0, stream>>>(x, idx1, W1a, b1a, W1b, b1b,
                                                 h, Hhi, Hlo, sq2);
  gemm_pq_kernel<<<(NPTS / 32) * 8, 256, 0, stream>>>(h, Wc, b2a, PQ);
  knn128_filter_kernel<<<(NPTS / 64) * JSPLIT, 256, 0, stream>>>(Hhi, Hlo, sq2, pi2);
  knn_rescore_kernel<<<NPTS / 4, 256, 0, stream>>>(h, sq2, pi2, idx2);
  edgeconv2_kernel<<<NPTS / 4, 256, 0, stream>>>(PQ, idx2, W2b, b2b, out);
}

// Round 7
// 667.990 us; speedup vs baseline: 7.6631x; 1.3464x over previous
//
#include <hip/hip_runtime.h>
#include <math.h>

constexpr int NPTS  = 8192;
constexpr int HIDC  = 128;
constexpr int OUTC2 = 256;
constexpr int PQC   = 512;
constexpr int KK1   = 16;
constexpr int KK2   = 8;

typedef __attribute__((ext_vector_type(8))) short short8;
typedef __attribute__((ext_vector_type(4))) float f32x4;

__device__ __forceinline__ f32x4 mfma16(short8 a, short8 b, f32x4 c) {
  return __builtin_amdgcn_mfma_f32_16x16x32_bf16(a, b, c, 0, 0, 0);
}

// pure strict-< insert (exact lex when per-lane stream has ascending j).
template <int K>
__device__ __forceinline__ void ins_f(float (&kf)[K], int (&ki)[K], float v, int j) {
  if (v < kf[K - 1]) {
    kf[K - 1] = v; ki[K - 1] = j;
    #pragma unroll
    for (int p = K - 1; p > 0; --p) {
      bool sw = kf[p] < kf[p - 1];
      float tf = kf[p - 1]; int ti = ki[p - 1];
      kf[p - 1] = sw ? kf[p] : tf;  ki[p - 1] = sw ? ki[p] : ti;
      kf[p]     = sw ? tf : kf[p];  ki[p]     = sw ? ti : ki[p];
    }
  }
}

// lexicographic (d, idx) insert — for merging lists whose idx order is mixed.
template <int K>
__device__ __forceinline__ void ins_lex(float (&kf)[K], int (&ki)[K], float v, int j) {
  bool ins = (v < kf[K - 1]) || (v == kf[K - 1] && j < ki[K - 1]);
  if (ins) {
    kf[K - 1] = v; ki[K - 1] = j;
    #pragma unroll
    for (int p = K - 1; p > 0; --p) {
      float fa = kf[p - 1], fb = kf[p];
      int   ia = ki[p - 1], ib = ki[p];
      bool sw = (fb < fa) || (fb == fa && ib < ia);
      kf[p - 1] = sw ? fb : fa; ki[p - 1] = sw ? ib : ia;
      kf[p]     = sw ? fa : fb; ki[p]     = sw ? ia : ib;
    }
  }
}

__device__ __forceinline__ unsigned short bf16_rn(float x) {
  unsigned int u = __float_as_uint(x);
  unsigned int r = u + 0x7fffu + ((u >> 16) & 1u);
  return (unsigned short)(r >> 16);
}

__device__ __forceinline__ float rdlane_f(float v, int l) {
  return __int_as_float(__builtin_amdgcn_readlane(__float_as_int(v), l));
}

// ---------------------------------------------------------------- pack x
__global__ void pack_x_kernel(const float* __restrict__ x, float4* __restrict__ x4) {
  int i = blockIdx.x * blockDim.x + threadIdx.x;
  if (i < NPTS) {
    float a = x[3 * i], b = x[3 * i + 1], c = x[3 * i + 2];
    x4[i] = make_float4(a, b, c, a * a + b * b + c * c);
  }
}

// ---------------------------------------------------------------- Wc = [Wl-Wh | Wh] for layer2 stage1
__global__ void prep_w1_kernel(const float* __restrict__ W1, float* __restrict__ Wc) {
  int idx = blockIdx.x * 256 + threadIdx.x;    // 128*512
  int k = idx >> 9, c = idx & 511;
  float wh = W1[(size_t)(HIDC + k) * OUTC2 + (c & 255)];
  Wc[idx] = (c < OUTC2) ? (W1[(size_t)k * OUTC2 + c] - wh) : wh;
}

// ---------------------------------------------------------------- KNN1 (C=3, K=16), ballot-scan
__global__ __launch_bounds__(256) void knn3_kernel(const float4* __restrict__ X4,
                                                   int* __restrict__ idx_out) {
  const int tid  = threadIdx.x;
  const int lane = tid & 63;
  const int wv   = __builtin_amdgcn_readfirstlane(tid >> 6);
  const int half = lane >> 5;           // which query of the wave
  const int l16  = lane & 15;           // list slot
  const bool listlane = (lane & 16) == 0;
  const int q0 = (blockIdx.x * 4 + wv) * 2;

  float qx[2], qy[2], qz[2], qw[2];
  #pragma unroll
  for (int q = 0; q < 2; ++q) {
    float4 v = X4[q0 + q];
    qx[q] = v.x; qy[q] = v.y; qz[q] = v.z; qw[q] = v.w;
  }

  float kd = INFINITY; int kj = 0x7fffffff;
  float wd[2]; int wj[2], ws[2];
  #pragma unroll
  for (int q = 0; q < 2; ++q) { wd[q] = INFINITY; wj[q] = 0x7fffffff; ws[q] = 0; }

  float4 pj = X4[lane];
  for (int j0 = 0; j0 < NPTS; j0 += 64) {
    float4 pjn = pj;
    if (j0 + 64 < NPTS) pjn = X4[j0 + 64 + lane];
    const int j = j0 + lane;
    #pragma unroll
    for (int q = 0; q < 2; ++q) {
      float d = qw[q] + pj.w - 2.f * (qx[q] * pj.x + qy[q] * pj.y + qz[q] * pj.z);
      bool c = (j != q0 + q) && ((d < wd[q]) || (d == wd[q] && j < wj[q]));
      unsigned long long vote = __ballot(c);
      while (vote) {
        const int l = (int)__ffsll(vote) - 1;
        vote &= vote - 1;
        const float dv = rdlane_f(d, l);
        const int   jv = j0 + l;
        if ((dv < wd[q]) || (dv == wd[q] && jv < wj[q])) {   // recheck vs CURRENT worst
          const bool mine = (half == q) && listlane && (l16 == ws[q]);
          kd = mine ? dv : kd;
          kj = mine ? jv : kj;
          float av = kd; int aj = kj; int as = l16;
          #pragma unroll
          for (int m = 1; m <= 8; m <<= 1) {
            float ov = __shfl_xor(av, m, 64);
            int   oj = __shfl_xor(aj, m, 64);
            int   os = __shfl_xor(as, m, 64);
            bool g = (ov > av) || (ov == av && oj > aj);
            av = g ? ov : av; aj = g ? oj : aj; as = g ? os : as;
          }
          wd[q] = rdlane_f(av, q * 32);
          wj[q] = __builtin_amdgcn_readlane(aj, q * 32);
          ws[q] = __builtin_amdgcn_readlane(as, q * 32);
        }
      }
    }
    pj = pjn;
  }
  if (listlane)
    idx_out[(size_t)(q0 + half) * KK1 + l16] = kj;
}

// ---------------------------------------------------------------- EdgeConv 1 (unchanged)
__global__ __launch_bounds__(256) void edgeconv1_kernel(
    const float* __restrict__ X, const int* __restrict__ knn,
    const float* __restrict__ W1, const float* __restrict__ b1,
    const float* __restrict__ W2, const float* __restrict__ b2,
    float* __restrict__ H, unsigned short* __restrict__ Hhi,
    unsigned short* __restrict__ Hlo, float* __restrict__ SQ2) {
  __shared__ float h1[8][KK1][HIDC];
  __shared__ float xjs[8][KK1][3];
  __shared__ float xis[8][3];
  const int tid  = threadIdx.x;
  const int lane = tid & 63;
  const int wv   = __builtin_amdgcn_readfirstlane(tid >> 6);
  const int half = lane >> 5;
  const int hl   = lane & 31;
  const int lp   = wv * 2 + half;
  const int p    = blockIdx.x * 8 + lp;
  const int ch0  = hl * 4;

  if (hl < KK1) {
    int j = knn[p * KK1 + hl];
    xjs[lp][hl][0] = X[3 * j]; xjs[lp][hl][1] = X[3 * j + 1]; xjs[lp][hl][2] = X[3 * j + 2];
  } else if (hl < KK1 + 3) {
    xis[lp][hl - KK1] = X[3 * p + hl - KK1];
  }
  __syncthreads();

  f32x4 w1r[6];
  #pragma unroll
  for (int c = 0; c < 6; ++c) w1r[c] = *(const f32x4*)&W1[c * HIDC + ch0];
  f32x4 b1v = *(const f32x4*)&b1[ch0];
  const float xi0 = xis[lp][0], xi1 = xis[lp][1], xi2 = xis[lp][2];
  f32x4 base;
  #pragma unroll
  for (int c = 0; c < 4; ++c)
    base[c] = b1v[c] + xi0 * w1r[0][c] + xi1 * w1r[1][c] + xi2 * w1r[2][c];
  #pragma unroll
  for (int e = 0; e < KK1; ++e) {
    float dx = xjs[lp][e][0] - xi0, dy = xjs[lp][e][1] - xi1, dz = xjs[lp][e][2] - xi2;
    f32x4 v;
    #pragma unroll
    for (int c = 0; c < 4; ++c)
      v[c] = fmaxf(base[c] + dx * w1r[3][c] + dy * w1r[4][c] + dz * w1r[5][c], 0.f);
    *(f32x4*)&h1[lp][e][ch0] = v;
  }
  __syncthreads();

  float acc[KK1][4];
  #pragma unroll
  for (int e = 0; e < KK1; ++e)
    #pragma unroll
    for (int c = 0; c < 4; ++c) acc[e][c] = 0.f;
  for (int c4 = 0; c4 < HIDC / 4; ++c4) {
    f32x4 w2r[4];
    #pragma unroll
    for (int cc = 0; cc < 4; ++cc)
      w2r[cc] = *(const f32x4*)&W2[(c4 * 4 + cc) * HIDC + ch0];
    #pragma unroll
    for (int e = 0; e < KK1; ++e) {
      f32x4 hv = *(const f32x4*)&h1[lp][e][c4 * 4];
      #pragma unroll
      for (int cc = 0; cc < 4; ++cc)
        #pragma unroll
        for (int c = 0; c < 4; ++c) acc[e][c] += hv[cc] * w2r[cc][c];
    }
  }
  f32x4 b2v = *(const f32x4*)&b2[ch0];
  f32x4 outv;
  #pragma unroll
  for (int c = 0; c < 4; ++c) {
    float m = -INFINITY;
    #pragma unroll
    for (int e = 0; e < KK1; ++e) m = fmaxf(m, acc[e][c]);
    outv[c] = m + b2v[c];
  }
  *(f32x4*)&H[(size_t)p * HIDC + ch0] = outv;

  unsigned short hb[4], lb[4];
  #pragma unroll
  for (int c = 0; c < 4; ++c) {
    hb[c] = bf16_rn(outv[c]);
    float fh = __uint_as_float(((unsigned int)hb[c]) << 16);
    lb[c] = bf16_rn(outv[c] - fh);
  }
  *(ushort4*)&Hhi[(size_t)p * HIDC + ch0] = make_ushort4(hb[0], hb[1], hb[2], hb[3]);
  *(ushort4*)&Hlo[(size_t)p * HIDC + ch0] = make_ushort4(lb[0], lb[1], lb[2], lb[3]);

  float s = outv[0]*outv[0] + outv[1]*outv[1] + outv[2]*outv[2] + outv[3]*outv[3];
  #pragma unroll
  for (int m = 1; m <= 16; m <<= 1) s += __shfl_xor(s, m, 64);
  if (hl == 0) SQ2[p] = s;
}

// ---------------------------------------------------------------- PQ = H @ Wc (+b1 on P half)
__global__ __launch_bounds__(256) void gemm_pq_kernel(
    const float* __restrict__ H, const float* __restrict__ Wc,
    const float* __restrict__ b1, float* __restrict__ PQ) {
  __shared__ float Hs[32][HIDC];
  const int tid = threadIdx.x;
  const int rb  = blockIdx.x >> 3;
  const int cb  = blockIdx.x & 7;
  const int col = cb * 64 + (tid & 63);
  const int rg  = tid >> 6;

  #pragma unroll
  for (int u = 0; u < 4; ++u) {
    int idx = u * 256 + tid;
    int r = idx >> 5, k4 = idx & 31;
    *(f32x4*)&Hs[r][k4 * 4] = *(const f32x4*)&H[(size_t)(rb * 32 + r) * HIDC + k4 * 4];
  }
  __syncthreads();

  float acc[8] = {};
  for (int k = 0; k < HIDC; ++k) {
    float w = Wc[(size_t)k * PQC + col];
    #pragma unroll
    for (int i = 0; i < 8; ++i) acc[i] += Hs[rg * 8 + i][k] * w;
  }
  const float bb = (col < OUTC2) ? b1[col] : 0.f;
  #pragma unroll
  for (int i = 0; i < 8; ++i)
    PQ[(size_t)(rb * 32 + rg * 8 + i) * PQC + col] = acc[i] + bb;
}

// ---------------------------------------------------------------- KNN2 filter (MFMA bf16x2, 3 terms)
// Per-lane top-8 over its 256-row stream, then in-wave kgroup merge
// (lanes ^16, ^32, same query) -> top-8 per (query, split). 64 cands/query.
constexpr int JSPLIT = 8;
constexpr int JPB2   = NPTS / JSPLIT;
constexpr int NT2    = JPB2 / 16;
constexpr int CPQ    = JSPLIT * KK2;   // 64 candidates per query

__global__ __launch_bounds__(256) void knn128_filter_kernel(
    const unsigned short* __restrict__ Hhi, const unsigned short* __restrict__ Hlo,
    const float* __restrict__ SQ, int* __restrict__ pi2) {
  const int tid  = threadIdx.x;
  const int lane = tid & 63;
  const int wv   = __builtin_amdgcn_readfirstlane(tid >> 6);
  const int qb   = blockIdx.x >> 3;
  const int js   = blockIdx.x & 7;
  const int col  = lane & 15;
  const int kg   = lane >> 4;
  const int qg   = qb * 64 + wv * 16 + col;

  short8 qhi[4], qlo[4];
  #pragma unroll
  for (int s = 0; s < 4; ++s) {
    const size_t o = (size_t)qg * HIDC + s * 32 + kg * 8;
    qhi[s] = *reinterpret_cast<const short8*>(Hhi + o);
    qlo[s] = *reinterpret_cast<const short8*>(Hlo + o);
  }
  const float sqq = SQ[qg];

  float kf[KK2]; int ki[KK2];
  #pragma unroll
  for (int k = 0; k < KK2; ++k) { kf[k] = INFINITY; ki[k] = 0x7fffffff; }

  const int jbase = js * JPB2;
  for (int it = 0; it < NT2; ++it) {
    const int jb = jbase + it * 16;
    const int arow = jb + col;
    short8 ahi[4], alo[4];
    #pragma unroll
    for (int s = 0; s < 4; ++s) {
      const size_t oa = (size_t)arow * HIDC + s * 32 + kg * 8;
      ahi[s] = *reinterpret_cast<const short8*>(Hhi + oa);
      alo[s] = *reinterpret_cast<const short8*>(Hlo + oa);
    }
    f32x4 sqjv = *reinterpret_cast<const f32x4*>(SQ + jb + kg * 4);

    f32x4 acc = {0.f, 0.f, 0.f, 0.f};
    #pragma unroll
    for (int s = 0; s < 4; ++s) {
      acc = mfma16(ahi[s], qhi[s], acc);
      acc = mfma16(ahi[s], qlo[s], acc);
      acc = mfma16(alo[s], qhi[s], acc);
    }
    #pragma unroll
    for (int r = 0; r < 4; ++r) {
      const int jg = jb + kg * 4 + r;
      float d = sqq + sqjv[r] - 2.f * acc[r];
      if (jg == qg) d = INFINITY;
      ins_f<KK2>(kf, ki, d, jg);
    }
  }

  // merge 4 kgroup lists (same query at lanes ^16, ^32) -> top-8 of split
  #pragma unroll
  for (int dlt = 16; dlt <= 32; dlt <<= 1) {
    float of[KK2]; int oi[KK2];
    #pragma unroll
    for (int k = 0; k < KK2; ++k) { of[k] = __shfl_xor(kf[k], dlt, 64); oi[k] = __shfl_xor(ki[k], dlt, 64); }
    #pragma unroll
    for (int k = 0; k < KK2; ++k) ins_lex<KK2>(kf, ki, of[k], oi[k]);
  }
  if (lane < 16) {
    const size_t base = (size_t)qg * CPQ + js * KK2;
    #pragma unroll
    for (int k = 0; k < KK2; ++k) pi2[base + k] = ki[k];
  }
}

// ---------------------------------------------------------------- exact fp32 rescore (64 cands, 1/lane)
__global__ __launch_bounds__(256) void knn_rescore_kernel(
    const float* __restrict__ H, const float* __restrict__ SQ,
    const int* __restrict__ pi2, int* __restrict__ idx_out) {
  const int tid  = threadIdx.x;
  const int wv   = tid >> 6;
  const int lane = tid & 63;
  const int q0   = blockIdx.x * 4;
  const int q    = q0 + wv;
  __shared__ float qrow[4][HIDC];
  for (int u = tid; u < 4 * HIDC; u += 256)
    qrow[u >> 7][u & 127] = H[(size_t)(q0 + (u >> 7)) * HIDC + (u & 127)];
  __syncthreads();

  const int ci = pi2[(size_t)q * CPQ + lane];
  const float* crow = H + (size_t)ci * HIDC;
  float dot = 0.f;
  #pragma unroll 8
  for (int c4 = 0; c4 < HIDC / 4; ++c4) {
    f32x4 qv = *(const f32x4*)&qrow[wv][c4 * 4];
    f32x4 cv = *(const f32x4*)(crow + c4 * 4);
    dot += qv[0] * cv[0] + qv[1] * cv[1] + qv[2] * cv[2] + qv[3] * cv[3];
  }
  float d = SQ[q] + SQ[ci] - 2.f * dot;

  float kf[KK2]; int ki[KK2];
  kf[0] = d; ki[0] = ci;
  #pragma unroll
  for (int k = 1; k < KK2; ++k) { kf[k] = INFINITY; ki[k] = 0x7fffffff; }
  #pragma unroll
  for (int dlt = 1; dlt <= 32; dlt <<= 1) {
    float of[KK2]; int oi[KK2];
    #pragma unroll
    for (int k = 0; k < KK2; ++k) { of[k] = __shfl_xor(kf[k], dlt, 64); oi[k] = __shfl_xor(ki[k], dlt, 64); }
    #pragma unroll
    for (int k = 0; k < KK2; ++k) ins_lex<KK2>(kf, ki, of[k], oi[k]);
  }
  if (lane == 0) {
    #pragma unroll
    for (int k = 0; k < KK2; ++k) idx_out[(size_t)q * KK2 + k] = ki[k];
  }
}

// ---------------------------------------------------------------- EdgeConv 2 (unchanged from R6)
__global__ __launch_bounds__(256) void edgeconv2_kernel(
    const float* __restrict__ PQ, const int* __restrict__ knn,
    const float* __restrict__ W2, const float* __restrict__ b2,
    float* __restrict__ Out) {
  __shared__ float g1[4][KK2][OUTC2];
  __shared__ float w2s[2][8][OUTC2];
  const int tid  = threadIdx.x;
  const int lane = tid & 63;
  const int wv   = __builtin_amdgcn_readfirstlane(tid >> 6);
  const int p    = blockIdx.x * 4 + wv;
  const int ch0  = lane * 4;

  f32x4 pv = *(const f32x4*)&PQ[(size_t)p * PQC + ch0];
  #pragma unroll
  for (int e = 0; e < KK2; ++e) {
    int j = knn[p * KK2 + e];
    f32x4 qv = *(const f32x4*)&PQ[(size_t)j * PQC + OUTC2 + ch0];
    f32x4 g;
    #pragma unroll
    for (int c = 0; c < 4; ++c) g[c] = fmaxf(pv[c] + qv[c], 0.f);
    *(f32x4*)&g1[wv][e][ch0] = g;
  }

  {
    int r = tid >> 5, c0 = (tid & 31) * 8;
    *(f32x4*)&w2s[0][r][c0]     = *(const f32x4*)&W2[(size_t)r * OUTC2 + c0];
    *(f32x4*)&w2s[0][r][c0 + 4] = *(const f32x4*)&W2[(size_t)r * OUTC2 + c0 + 4];
  }
  __syncthreads();

  float acc2[KK2][4];
  #pragma unroll
  for (int e = 0; e < KK2; ++e)
    #pragma unroll
    for (int c = 0; c < 4; ++c) acc2[e][c] = 0.f;

  for (int c8 = 0; c8 < OUTC2 / 8; ++c8) {
    const int cur = c8 & 1;
    if (c8 + 1 < OUTC2 / 8) {
      int r = tid >> 5, c0 = (tid & 31) * 8;
      int gr = (c8 + 1) * 8 + r;
      *(f32x4*)&w2s[cur ^ 1][r][c0]     = *(const f32x4*)&W2[(size_t)gr * OUTC2 + c0];
      *(f32x4*)&w2s[cur ^ 1][r][c0 + 4] = *(const f32x4*)&W2[(size_t)gr * OUTC2 + c0 + 4];
    }
    f32x4 wreg[8];
    #pragma unroll
    for (int cc = 0; cc < 8; ++cc) wreg[cc] = *(const f32x4*)&w2s[cur][cc][ch0];
    #pragma unroll
    for (int e = 0; e < KK2; ++e) {
      f32x4 gv0 = *(const f32x4*)&g1[wv][e][c8 * 8];
      f32x4 gv1 = *(const f32x4*)&g1[wv][e][c8 * 8 + 4];
      #pragma unroll
      for (int cc = 0; cc < 4; ++cc)
        #pragma unroll
        for (int c = 0; c < 4; ++c) acc2[e][c] += gv0[cc] * wreg[cc][c];
      #pragma unroll
      for (int cc = 0; cc < 4; ++cc)
        #pragma unroll
        for (int c = 0; c < 4; ++c) acc2[e][c] += gv1[cc] * wreg[4 + cc][c];
    }
    __syncthreads();
  }

  f32x4 b2v = *(const f32x4*)&b2[ch0];
  f32x4 outv;
  #pragma unroll
  for (int c = 0; c < 4; ++c) {
    float m = -INFINITY;
    #pragma unroll
    for (int e = 0; e < KK2; ++e) m = fmaxf(m, acc2[e][c]);
    outv[c] = m + b2v[c];
  }
  *(f32x4*)&Out[(size_t)p * OUTC2 + ch0] = outv;
}

// ---------------------------------------------------------------- launch
extern "C" void kernel_launch(void* const* d_in, const int* in_sizes, int n_in,
                              void* d_out, int out_size, void* d_ws, size_t ws_size,
                              hipStream_t stream) {
  const float* x   = (const float*)d_in[0];
  const float* W1a = (const float*)d_in[1];
  const float* b1a = (const float*)d_in[2];
  const float* W1b = (const float*)d_in[3];
  const float* b1b = (const float*)d_in[4];
  const float* W2a = (const float*)d_in[5];
  const float* b2a = (const float*)d_in[6];
  const float* W2b = (const float*)d_in[7];
  const float* b2b = (const float*)d_in[8];
  float* out = (float*)d_out;

  float* h    = (float*)d_ws;                       // 4 MB
  float* sq2  = h + (size_t)NPTS * HIDC;
  int*   idx1 = (int*)(sq2 + NPTS);
  int*   idx2 = idx1 + (size_t)NPTS * KK1;
  unsigned short* Hhi = (unsigned short*)(idx2 + (size_t)NPTS * KK2);  // 2 MB
  unsigned short* Hlo = Hhi + (size_t)NPTS * HIDC;                     // 2 MB
  int*   pi2  = (int*)(Hlo + (size_t)NPTS * HIDC);  // 8192*64*4 = 2 MB
  float* Wc   = (float*)(pi2 + (size_t)NPTS * CPQ); // 256 KB
  float* PQ   = Wc + (size_t)HIDC * PQC;            // 16 MB
  // x4 aliases h's first 128KB: knn3 finishes before edgeconv1 writes h.
  float4* x4 = (float4*)h;

  pack_x_kernel<<<(NPTS + 255) / 256, 256, 0, stream>>>(x, x4);
  prep_w1_kernel<<<(HIDC * PQC) / 256, 256, 0, stream>>>(W2a, Wc);
  knn3_kernel<<<NPTS / 8, 256, 0, stream>>>(x4, idx1);
  edgeconv1_kernel<<<NPTS / 8, 256, 0, stream>>>(x, idx1, W1a, b1a, W1b, b1b,
                                                 h, Hhi, Hlo, sq2);
  gemm_pq_kernel<<<(NPTS / 32) * 8, 256, 0, stream>>>(h, Wc, b2a, PQ);
  knn128_filter_kernel<<<(NPTS / 64) * JSPLIT, 256, 0, stream>>>(Hhi, Hlo, sq2, pi2);
  knn_rescore_kernel<<<NPTS / 4, 256, 0, stream>>>(h, sq2, pi2, idx2);
  edgeconv2_kernel<<<NPTS / 4, 256, 0, stream>>>(PQ, idx2, W2b, b2b, out);
}